// Round 2
// baseline (1179.474 us; speedup 1.0000x reference)
//
#include <hip/hip_runtime.h>
#include <hip/hip_bf16.h>
#include <cstddef>

#define NG   50000
#define ND   20000
#define DH   128
#define EGG  800000
#define EGDA 400000
#define ELAB 200000

typedef __hip_bfloat16  bf16;
typedef __attribute__((ext_vector_type(8))) short bf16x8;
typedef __attribute__((ext_vector_type(4))) float f32x4;

// split float into hi/lo bf16 bit-patterns (truncation; x - hi is exact)
__device__ __forceinline__ void split_bf(float x, short& h, short& l){
  unsigned u = __float_as_uint(x);
  h = (short)(u >> 16);
  float r = x - __uint_as_float(u & 0xFFFF0000u);
  l = (short)(__float_as_uint(r) >> 16);
}

// ---------------- CSR build ----------------
__global__ void k_count(const int* __restrict__ key, int n, int* __restrict__ deg){
  for (int i = blockIdx.x*blockDim.x + threadIdx.x; i < n; i += gridDim.x*blockDim.x)
    atomicAdd(&deg[key[i]], 1);
}

__global__ __launch_bounds__(1024) void k_exscan(const int* __restrict__ cnt, int* __restrict__ ptr, int n){
  __shared__ int wsum[16];
  __shared__ int carry;
  const int tid = threadIdx.x, lane = tid & 63, wid = tid >> 6;
  if (tid == 0) carry = 0;
  __syncthreads();
  for (int base = 0; base < n; base += 1024){
    int v = (base + tid < n) ? cnt[base + tid] : 0;
    int x = v;
    #pragma unroll
    for (int off = 1; off < 64; off <<= 1){
      int t = __shfl_up(x, off);
      if (lane >= off) x += t;
    }
    if (lane == 63) wsum[wid] = x;
    __syncthreads();
    if (wid == 0 && lane < 16){
      int w = wsum[lane];
      #pragma unroll
      for (int off = 1; off < 16; off <<= 1){
        int t = __shfl_up(w, off);
        if (lane >= off) w += t;
      }
      wsum[lane] = w;
    }
    __syncthreads();
    int waveoff = wid ? wsum[wid-1] : 0;
    if (base + tid < n) ptr[base + tid] = carry + waveoff + x - v;
    int total = wsum[15];
    __syncthreads();
    if (tid == 0) carry += total;
    __syncthreads();
  }
  if (threadIdx.x == 0) ptr[n] = carry;
}

__global__ void k_copy_int(const int* __restrict__ src, int* __restrict__ dst, int n){
  int i = blockIdx.x*blockDim.x + threadIdx.x;
  if (i < n) dst[i] = src[i];
}

__global__ void k_fill(const int* __restrict__ key, const int* __restrict__ val, int n,
                       int* __restrict__ cur, int* __restrict__ col){
  for (int i = blockIdx.x*blockDim.x + threadIdx.x; i < n; i += gridDim.x*blockDim.x){
    int p = atomicAdd(&cur[key[i]], 1);
    col[p] = val[i];
  }
}

// ---------------- weight composition (fp32) ----------------
// AB layout: mat = i*2 + isB: A_i = Wd[i]@Wu_top[i], B_i = Ws[i]@Wu_bot[i]
__global__ void k_compose_AB(const float* __restrict__ Wd, const float* __restrict__ Ws,
                             const float* __restrict__ Wu, float* __restrict__ AB){
  int idx = blockIdx.x*256 + threadIdx.x;      // 6*16384
  int mat = idx >> 14;
  int r   = (idx >> 7) & 127;
  int c   = idx & 127;
  int i   = mat >> 1;
  int isB = mat & 1;
  const float* P = (isB ? Ws : Wd) + i*16384 + r*128;
  const float* Q = Wu + i*32768 + (isB ? 16384 : 0) + c;
  float s = 0.f;
  for (int h = 0; h < 128; ++h) s += P[h] * Q[h*128];
  AB[idx] = s;
}

__global__ void k_compose_bias(const float* __restrict__ bd, const float* __restrict__ bs,
                               const float* __restrict__ bu, const float* __restrict__ Wu,
                               float* __restrict__ cv){
  int idx = blockIdx.x*256 + threadIdx.x;      // 3*128
  if (idx >= 384) return;
  int i = idx >> 7, h = idx & 127;
  float s = bu[i*128 + h];
  const float* Ut = Wu + i*32768 + h;
  const float* Ub = Ut + 16384;
  for (int k = 0; k < 128; ++k)
    s += bd[i*128 + k] * Ut[k*128] + bs[i*128 + k] * Ub[k*128];
  cv[idx] = s;
}

// pack B-fragment order, hi/lo interleaved per fragment:
// f = (n0*KS + ks)*64 + lane ; Wp[f*16 + j] = hi_j, Wp[f*16 + 8 + j] = lo_j
// where element = W[k = ks*32+(lane>>4)*8+j][n0*16+(lane&15)]
__global__ void k_pack_gene(const float* __restrict__ AB, const float* __restrict__ cv,
                            bf16* __restrict__ Wp, float* __restrict__ cg){
  int idx = blockIdx.x*256 + threadIdx.x;      // 8*12*512 = 49152
  int n0  = idx / 6144;
  int rem = idx - n0*6144;
  int ks  = rem >> 9;
  int lane = (rem >> 3) & 63;
  int j   = rem & 7;
  int k   = ks*32 + (lane >> 4)*8 + j;
  int col = n0*16 + (lane & 15);
  float v;
  if      (k < 128) v = 0.5f*(AB[0*16384 + k*128 + col] + AB[4*16384 + k*128 + col]);
  else if (k < 256) v = 0.5f* AB[1*16384 + (k-128)*128 + col];
  else              v = 0.5f* AB[5*16384 + (k-256)*128 + col];
  short h, l; split_bf(v, h, l);
  int f = idx >> 3;          // (n0*KS+ks)*64 + lane
  ((short*)Wp)[f*16 + j]     = h;
  ((short*)Wp)[f*16 + 8 + j] = l;
  if (idx < 128) cg[idx] = 0.5f*(cv[idx] + cv[256 + idx]);
}

__global__ void k_pack_dis(const float* __restrict__ AB, const float* __restrict__ cv,
                           bf16* __restrict__ Wp, float* __restrict__ cd){
  int idx = blockIdx.x*256 + threadIdx.x;      // 8*8*512 = 32768
  int n0  = idx >> 12;
  int ks  = (idx >> 9) & 7;
  int lane = (idx >> 3) & 63;
  int j   = idx & 7;
  int k   = ks*32 + (lane >> 4)*8 + j;
  int col = n0*16 + (lane & 15);
  float v = (k < 128) ? AB[2*16384 + k*128 + col] : AB[3*16384 + (k-128)*128 + col];
  short h, l; split_bf(v, h, l);
  int f = idx >> 3;
  ((short*)Wp)[f*16 + j]     = h;
  ((short*)Wp)[f*16 + 8 + j] = l;
  if (idx < 128) cd[idx] = cv[128 + idx];
}

// ---------------- mean aggregation (wave per dst, fp32) ----------------
__global__ __launch_bounds__(256) void k_agg_mean(const float* __restrict__ X,
    const int* __restrict__ ptr, const int* __restrict__ col,
    float* __restrict__ Out, int N){
  int w = (blockIdx.x*blockDim.x + threadIdx.x) >> 6;
  int lane = threadIdx.x & 63;
  if (w >= N) return;
  int s = ptr[w], e = ptr[w+1];
  float a0 = 0.f, a1 = 0.f;
  for (int i = s; i < e; ++i){
    int src = col[i];
    float2 v = *(const float2*)(X + (size_t)src*DH + lane*2);
    a0 += v.x; a1 += v.y;
  }
  float inv = 1.f / fmaxf((float)(e - s), 1.f);
  float2 o; o.x = a0*inv; o.y = a1*inv;
  *(float2*)(Out + (size_t)w*DH + lane*2) = o;
}

// ---------------- concat-K split-bf16 MFMA GEMM ----------------
// C[M x 128] = [X0|X1|X2] @ W + cvec, KS = K/32 (12 gene, 8 disease), fp32 in/out
__global__ __launch_bounds__(256) void k_gemm_cat(
    const float* __restrict__ X0, const float* __restrict__ X1, const float* __restrict__ X2,
    const bf16* __restrict__ Wp, const float* __restrict__ cvec,
    float* __restrict__ Out, int M, int KS){
  const int wave = threadIdx.x >> 6;
  const int lane = threadIdx.x & 63;
  const int lrow = lane & 15, quad = lane >> 4;
  const int row0 = blockIdx.x*64 + wave*16;
  int arow = row0 + lrow; if (arow > M-1) arow = M-1;
  const float* Xs[3] = {X0, X1, X2};
  f32x4 acc[8];
  #pragma unroll
  for (int i = 0; i < 8; ++i) acc[i] = 0.0f;
  const bf16x8* wp = (const bf16x8*)Wp;
  for (int ks = 0; ks < KS; ++ks){
    const float* ap = Xs[ks >> 2] + (size_t)arow*DH + (ks & 3)*32 + quad*8;
    float4 a0 = ((const float4*)ap)[0];
    float4 a1 = ((const float4*)ap)[1];
    float av[8] = {a0.x,a0.y,a0.z,a0.w,a1.x,a1.y,a1.z,a1.w};
    bf16x8 ahi, alo;
    #pragma unroll
    for (int j = 0; j < 8; ++j){
      short h, l; split_bf(av[j], h, l);
      ahi[j] = h; alo[j] = l;
    }
    #pragma unroll
    for (int n0 = 0; n0 < 8; ++n0){
      int f = (n0*KS + ks)*64 + lane;
      bf16x8 bhi = wp[f*2];
      bf16x8 blo = wp[f*2 + 1];
      acc[n0] = __builtin_amdgcn_mfma_f32_16x16x32_bf16(ahi, bhi, acc[n0], 0, 0, 0);
      acc[n0] = __builtin_amdgcn_mfma_f32_16x16x32_bf16(alo, bhi, acc[n0], 0, 0, 0);
      acc[n0] = __builtin_amdgcn_mfma_f32_16x16x32_bf16(ahi, blo, acc[n0], 0, 0, 0);
    }
  }
  #pragma unroll
  for (int n0 = 0; n0 < 8; ++n0){
    int col = n0*16 + lrow;
    float cb = cvec[col];
    #pragma unroll
    for (int r = 0; r < 4; ++r){
      int row = row0 + quad*4 + r;
      if (row < M) Out[(size_t)row*DH + col] = acc[n0][r] + cb;
    }
  }
}

// ---------------- BatchNorm (training stats) + LeakyReLU ----------------
__global__ __launch_bounds__(256) void k_bn_stats(const float* __restrict__ X, int N,
                                                  float* __restrict__ sums){
  int tid = threadIdx.x;
  int c = tid & 127, half = tid >> 7;
  float s = 0.f, ss = 0.f;
  for (int r = blockIdx.x*2 + half; r < N; r += gridDim.x*2){
    float v = X[(size_t)r*DH + c];
    s += v; ss += v*v;
  }
  __shared__ float sh[512];
  sh[tid] = s; sh[256 + tid] = ss;
  __syncthreads();
  if (tid < 128){
    atomicAdd(&sums[c],       sh[tid]       + sh[tid + 128]);
    atomicAdd(&sums[128 + c], sh[256 + tid] + sh[256 + tid + 128]);
  }
}

__global__ __launch_bounds__(256) void k_bn_apply(const float* __restrict__ X,
    const float* __restrict__ sums, const float* __restrict__ gamma, const float* __restrict__ beta,
    float* __restrict__ Y, int total, float invN){
  for (int idx = blockIdx.x*blockDim.x + threadIdx.x; idx < total; idx += gridDim.x*blockDim.x){
    int c = idx & 127;
    float m = sums[c]*invN;
    float v = sums[128 + c]*invN - m*m;
    float sc = rsqrtf(v + 1e-5f) * gamma[c];
    float y = (X[idx] - m)*sc + beta[c];
    Y[idx] = (y >= 0.f ? y : 0.01f*y);
  }
}

// ---------------- decoder (wave per label edge, fp32 out) ----------------
__global__ __launch_bounds__(256) void k_decode(const float* __restrict__ G, const float* __restrict__ Dd,
    const int* __restrict__ ls, const int* __restrict__ ld, float* __restrict__ out, int E){
  int w = (blockIdx.x*blockDim.x + threadIdx.x) >> 6;
  int lane = threadIdx.x & 63;
  if (w >= E) return;
  int a = ls[w], b = ld[w];
  float2 gv = *(const float2*)(G  + (size_t)a*DH + lane*2);
  float2 dv = *(const float2*)(Dd + (size_t)b*DH + lane*2);
  float s = gv.x*dv.x + gv.y*dv.y;
  #pragma unroll
  for (int off = 32; off; off >>= 1) s += __shfl_down(s, off);
  if (lane == 0) out[w] = s;
}

// ---------------- launch ----------------
extern "C" void kernel_launch(void* const* d_in, const int* in_sizes, int n_in,
                              void* d_out, int out_size, void* d_ws, size_t ws_size,
                              hipStream_t stream){
  const float* x_gene = (const float*)d_in[0];
  const float* x_dis  = (const float*)d_in[1];
  const float* Wd1 = (const float*)d_in[2];
  const float* Ws1 = (const float*)d_in[3];
  const float* Wu1 = (const float*)d_in[4];
  const float* bd1 = (const float*)d_in[5];
  const float* bs1 = (const float*)d_in[6];
  const float* bu1 = (const float*)d_in[7];
  const float* Wd2 = (const float*)d_in[8];
  const float* Ws2 = (const float*)d_in[9];
  const float* Wu2 = (const float*)d_in[10];
  const float* bd2 = (const float*)d_in[11];
  const float* bs2 = (const float*)d_in[12];
  const float* bu2 = (const float*)d_in[13];
  const float* bng = (const float*)d_in[14];
  const float* bnb = (const float*)d_in[15];
  const int* gg_src  = (const int*)d_in[16];
  const int* gg_dst  = (const int*)d_in[17];
  const int* gda_src = (const int*)d_in[18];
  const int* gda_dst = (const int*)d_in[19];
  const int* lsrc = (const int*)d_in[20];
  const int* ldst = (const int*)d_in[21];

  char* ws = (char*)d_ws;
  size_t off = 0;
  auto alloc = [&](size_t bytes)->void*{
    void* p = ws + off; off += (bytes + 255) & ~(size_t)255; return p;
  };
  int* gg_ptr  = (int*)alloc((NG+1)*4);
  int* gg_col  = (int*)alloc((size_t)EGG*4);
  int* gda_ptr = (int*)alloc((ND+1)*4);
  int* gda_col = (int*)alloc((size_t)EGDA*4);
  int* rev_ptr = (int*)alloc((NG+1)*4);
  int* rev_col = (int*)alloc((size_t)EGDA*4);
  int* tmp     = (int*)alloc((size_t)NG*4);
  float* AB1 = (float*)alloc(6*16384*4);
  float* AB2 = (float*)alloc(6*16384*4);
  float* cv1 = (float*)alloc(3*128*4);
  float* cv2 = (float*)alloc(3*128*4);
  float* cg1 = (float*)alloc(128*4);
  float* cd1 = (float*)alloc(128*4);
  float* cg2 = (float*)alloc(128*4);
  float* cd2 = (float*)alloc(128*4);
  bf16* Wg1  = (bf16*)alloc(98304*2);   // hi/lo interleaved
  bf16* Wp1  = (bf16*)alloc(65536*2);
  bf16* Wg2  = (bf16*)alloc(98304*2);
  bf16* Wp2  = (bf16*)alloc(65536*2);
  float* aggGG  = (float*)alloc((size_t)NG*DH*4);
  float* aggREV = (float*)alloc((size_t)NG*DH*4);
  float* aggGDA = (float*)alloc((size_t)ND*DH*4);
  float* Xg2 = (float*)alloc((size_t)NG*DH*4);
  float* Xd2 = (float*)alloc((size_t)ND*DH*4);
  float* outg = (float*)alloc((size_t)NG*DH*4);
  float* outd = (float*)alloc((size_t)ND*DH*4);
  float* bnsum = (float*)alloc(2*256*4);

  // --- CSR: gene->gene grouped by gg_dst ---
  hipMemsetAsync(tmp, 0, NG*4, stream);
  k_count<<<512,256,0,stream>>>(gg_dst, EGG, tmp);
  k_exscan<<<1,1024,0,stream>>>(tmp, gg_ptr, NG);
  k_copy_int<<<(NG+255)/256,256,0,stream>>>(gg_ptr, tmp, NG);
  k_fill<<<512,256,0,stream>>>(gg_dst, gg_src, EGG, tmp, gg_col);
  // --- CSR: gene->disease grouped by gda_dst ---
  hipMemsetAsync(tmp, 0, ND*4, stream);
  k_count<<<512,256,0,stream>>>(gda_dst, EGDA, tmp);
  k_exscan<<<1,1024,0,stream>>>(tmp, gda_ptr, ND);
  k_copy_int<<<(ND+255)/256,256,0,stream>>>(gda_ptr, tmp, ND);
  k_fill<<<512,256,0,stream>>>(gda_dst, gda_src, EGDA, tmp, gda_col);
  // --- CSR: disease->gene (reverse) grouped by gda_src ---
  hipMemsetAsync(tmp, 0, NG*4, stream);
  k_count<<<512,256,0,stream>>>(gda_src, EGDA, tmp);
  k_exscan<<<1,1024,0,stream>>>(tmp, rev_ptr, NG);
  k_copy_int<<<(NG+255)/256,256,0,stream>>>(rev_ptr, tmp, NG);
  k_fill<<<512,256,0,stream>>>(gda_src, gda_dst, EGDA, tmp, rev_col);

  // --- composed weights (both layers) ---
  k_compose_AB<<<384,256,0,stream>>>(Wd1, Ws1, Wu1, AB1);
  k_compose_AB<<<384,256,0,stream>>>(Wd2, Ws2, Wu2, AB2);
  k_compose_bias<<<2,256,0,stream>>>(bd1, bs1, bu1, Wu1, cv1);
  k_compose_bias<<<2,256,0,stream>>>(bd2, bs2, bu2, Wu2, cv2);
  k_pack_gene<<<192,256,0,stream>>>(AB1, cv1, Wg1, cg1);
  k_pack_gene<<<192,256,0,stream>>>(AB2, cv2, Wg2, cg2);
  k_pack_dis<<<128,256,0,stream>>>(AB1, cv1, Wp1, cd1);
  k_pack_dis<<<128,256,0,stream>>>(AB2, cv2, Wp2, cd2);

  // --- layer 1 ---
  k_agg_mean<<<NG/4,256,0,stream>>>(x_gene, gg_ptr, gg_col, aggGG, NG);
  k_agg_mean<<<ND/4,256,0,stream>>>(x_gene, gda_ptr, gda_col, aggGDA, ND);
  k_agg_mean<<<NG/4,256,0,stream>>>(x_dis, rev_ptr, rev_col, aggREV, NG);
  k_gemm_cat<<<(NG+63)/64,256,0,stream>>>(x_gene, aggGG, aggREV, Wg1, cg1, outg, NG, 12);
  k_gemm_cat<<<(ND+63)/64,256,0,stream>>>(x_dis, aggGDA, aggGDA, Wp1, cd1, outd, ND, 8);
  hipMemsetAsync(bnsum, 0, 2*256*4, stream);
  k_bn_stats<<<64,256,0,stream>>>(outg, NG, bnsum);
  k_bn_stats<<<64,256,0,stream>>>(outd, ND, bnsum + 256);
  k_bn_apply<<<1024,256,0,stream>>>(outg, bnsum, bng, bnb, Xg2, NG*DH, 1.f/NG);
  k_bn_apply<<<1024,256,0,stream>>>(outd, bnsum + 256, bng + 128, bnb + 128, Xd2, ND*DH, 1.f/ND);

  // --- layer 2 ---
  k_agg_mean<<<NG/4,256,0,stream>>>(Xg2, gg_ptr, gg_col, aggGG, NG);
  k_agg_mean<<<ND/4,256,0,stream>>>(Xg2, gda_ptr, gda_col, aggGDA, ND);
  k_agg_mean<<<NG/4,256,0,stream>>>(Xd2, rev_ptr, rev_col, aggREV, NG);
  k_gemm_cat<<<(NG+63)/64,256,0,stream>>>(Xg2, aggGG, aggREV, Wg2, cg2, outg, NG, 12);
  k_gemm_cat<<<(ND+63)/64,256,0,stream>>>(Xd2, aggGDA, aggGDA, Wp2, cd2, outd, ND, 8);

  // --- decoder ---
  k_decode<<<ELAB/4,256,0,stream>>>(outg, outd, lsrc, ldst, (float*)d_out, ELAB);
}

// Round 3
// 939.533 us; speedup vs baseline: 1.2554x; 1.2554x over previous
//
#include <hip/hip_runtime.h>
#include <hip/hip_bf16.h>
#include <cstddef>

#define NG   50000
#define ND   20000
#define DH   128
#define EGG  800000
#define EGDA 400000
#define ELAB 200000

typedef __hip_bfloat16  bf16;
typedef __attribute__((ext_vector_type(8))) short bf16x8;
typedef __attribute__((ext_vector_type(4))) float f32x4;

// split float into hi/lo bf16 bit-patterns (truncation; x - hi is exact)
__device__ __forceinline__ void split_bf(float x, short& h, short& l){
  unsigned u = __float_as_uint(x);
  h = (short)(u >> 16);
  float r = x - __uint_as_float(u & 0xFFFF0000u);
  l = (short)(__float_as_uint(r) >> 16);
}

// ---------------- CSR build ----------------
__global__ void k_count(const int* __restrict__ key, int n, int* __restrict__ deg){
  for (int i = blockIdx.x*blockDim.x + threadIdx.x; i < n; i += gridDim.x*blockDim.x)
    atomicAdd(&deg[key[i]], 1);
}

// n must be a multiple of 4 (true for NG, ND)
__global__ __launch_bounds__(1024) void k_exscan(const int* __restrict__ cnt, int* __restrict__ ptr, int n){
  __shared__ int wsum[16];
  __shared__ int carry;
  const int tid = threadIdx.x, lane = tid & 63, wid = tid >> 6;
  if (tid == 0) carry = 0;
  __syncthreads();
  for (int base = 0; base < n; base += 4096){
    int i0 = base + tid*4;
    int4 v = {0,0,0,0};
    if (i0 < n) v = *(const int4*)(cnt + i0);
    int tsum = v.x + v.y + v.z + v.w;
    int x = tsum;
    #pragma unroll
    for (int off = 1; off < 64; off <<= 1){
      int t = __shfl_up(x, off);
      if (lane >= off) x += t;
    }
    if (lane == 63) wsum[wid] = x;
    __syncthreads();
    if (wid == 0 && lane < 16){
      int w = wsum[lane];
      #pragma unroll
      for (int off = 1; off < 16; off <<= 1){
        int t = __shfl_up(w, off);
        if (lane >= off) w += t;
      }
      wsum[lane] = w;
    }
    __syncthreads();
    int waveoff = wid ? wsum[wid-1] : 0;
    if (i0 < n){
      int ex = carry + waveoff + x - tsum;
      int4 o;
      o.x = ex; o.y = ex + v.x; o.z = o.y + v.y; o.w = o.z + v.z;
      *(int4*)(ptr + i0) = o;
    }
    int total = wsum[15];
    __syncthreads();
    if (tid == 0) carry += total;
    __syncthreads();
  }
  if (tid == 0) ptr[n] = carry;
}

__global__ void k_copy_int(const int* __restrict__ src, int* __restrict__ dst, int n){
  int i = blockIdx.x*blockDim.x + threadIdx.x;
  if (i < n) dst[i] = src[i];
}

__global__ void k_fill(const int* __restrict__ key, const int* __restrict__ val, int n,
                       int* __restrict__ cur, int* __restrict__ col){
  for (int i = blockIdx.x*blockDim.x + threadIdx.x; i < n; i += gridDim.x*blockDim.x){
    int p = atomicAdd(&cur[key[i]], 1);
    col[p] = val[i];
  }
}

// ---------------- weight composition (fp32) ----------------
__global__ void k_compose_AB(const float* __restrict__ Wd, const float* __restrict__ Ws,
                             const float* __restrict__ Wu, float* __restrict__ AB){
  int idx = blockIdx.x*256 + threadIdx.x;      // 6*16384
  int mat = idx >> 14;
  int r   = (idx >> 7) & 127;
  int c   = idx & 127;
  int i   = mat >> 1;
  int isB = mat & 1;
  const float* P = (isB ? Ws : Wd) + i*16384 + r*128;
  const float* Q = Wu + i*32768 + (isB ? 16384 : 0) + c;
  float s = 0.f;
  for (int h = 0; h < 128; ++h) s += P[h] * Q[h*128];
  AB[idx] = s;
}

__global__ void k_compose_bias(const float* __restrict__ bd, const float* __restrict__ bs,
                               const float* __restrict__ bu, const float* __restrict__ Wu,
                               float* __restrict__ cv){
  int idx = blockIdx.x*256 + threadIdx.x;      // 3*128
  if (idx >= 384) return;
  int i = idx >> 7, h = idx & 127;
  float s = bu[i*128 + h];
  const float* Ut = Wu + i*32768 + h;
  const float* Ub = Ut + 16384;
  for (int k = 0; k < 128; ++k)
    s += bd[i*128 + k] * Ut[k*128] + bs[i*128 + k] * Ub[k*128];
  cv[idx] = s;
}

// pack B-fragment order, hi/lo interleaved per fragment
__global__ void k_pack_gene(const float* __restrict__ AB, const float* __restrict__ cv,
                            bf16* __restrict__ Wp, float* __restrict__ cg){
  int idx = blockIdx.x*256 + threadIdx.x;      // 8*12*512 = 49152
  int n0  = idx / 6144;
  int rem = idx - n0*6144;
  int ks  = rem >> 9;
  int lane = (rem >> 3) & 63;
  int j   = rem & 7;
  int k   = ks*32 + (lane >> 4)*8 + j;
  int col = n0*16 + (lane & 15);
  float v;
  if      (k < 128) v = 0.5f*(AB[0*16384 + k*128 + col] + AB[4*16384 + k*128 + col]);
  else if (k < 256) v = 0.5f* AB[1*16384 + (k-128)*128 + col];
  else              v = 0.5f* AB[5*16384 + (k-256)*128 + col];
  short h, l; split_bf(v, h, l);
  int f = idx >> 3;
  ((short*)Wp)[f*16 + j]     = h;
  ((short*)Wp)[f*16 + 8 + j] = l;
  if (idx < 128) cg[idx] = 0.5f*(cv[idx] + cv[256 + idx]);
}

__global__ void k_pack_dis(const float* __restrict__ AB, const float* __restrict__ cv,
                           bf16* __restrict__ Wp, float* __restrict__ cd){
  int idx = blockIdx.x*256 + threadIdx.x;      // 8*8*512 = 32768
  int n0  = idx >> 12;
  int ks  = (idx >> 9) & 7;
  int lane = (idx >> 3) & 63;
  int j   = idx & 7;
  int k   = ks*32 + (lane >> 4)*8 + j;
  int col = n0*16 + (lane & 15);
  float v = (k < 128) ? AB[2*16384 + k*128 + col] : AB[3*16384 + (k-128)*128 + col];
  short h, l; split_bf(v, h, l);
  int f = idx >> 3;
  ((short*)Wp)[f*16 + j]     = h;
  ((short*)Wp)[f*16 + 8 + j] = l;
  if (idx < 128) cd[idx] = cv[128 + idx];
}

// ---------------- mean aggregation (half-wave per dst, float4) ----------------
__global__ __launch_bounds__(256) void k_agg_mean(const float* __restrict__ X,
    const int* __restrict__ ptr, const int* __restrict__ col,
    float* __restrict__ Out, int N){
  int h = (blockIdx.x*blockDim.x + threadIdx.x) >> 5;
  int lane = threadIdx.x & 31;
  if (h >= N) return;
  int s = ptr[h], e = ptr[h+1];
  float4 a = {0.f,0.f,0.f,0.f};
  for (int i = s; i < e; ++i){
    int src = col[i];
    float4 v = *(const float4*)(X + (size_t)src*DH + lane*4);
    a.x += v.x; a.y += v.y; a.z += v.z; a.w += v.w;
  }
  float inv = 1.f / fmaxf((float)(e - s), 1.f);
  a.x *= inv; a.y *= inv; a.z *= inv; a.w *= inv;
  *(float4*)(Out + (size_t)h*DH + lane*4) = a;
}

// ---------------- concat-K split-bf16 MFMA GEMM (64 rows/wave) ----------------
// C[M x 128] = [X0|X1|X2] @ W + cvec, KS = K/32 (12 gene, 8 disease)
__global__ __launch_bounds__(256) void k_gemm_cat(
    const float* __restrict__ X0, const float* __restrict__ X1, const float* __restrict__ X2,
    const bf16* __restrict__ Wp, const float* __restrict__ cvec,
    float* __restrict__ Out, int M, int KS){
  const int wave = threadIdx.x >> 6;
  const int lane = threadIdx.x & 63;
  const int lrow = lane & 15, quad = lane >> 4;
  const int wrow0 = blockIdx.x*256 + wave*64;
  const float* Xs[3] = {X0, X1, X2};
  f32x4 acc[8][4];
  #pragma unroll
  for (int i = 0; i < 8; ++i)
    #pragma unroll
    for (int t = 0; t < 4; ++t) acc[i][t] = 0.0f;
  const bf16x8* wp = (const bf16x8*)Wp;
  for (int ks = 0; ks < KS; ++ks){
    const float* Xm = Xs[ks >> 2];
    int kk = (ks & 3)*32 + quad*8;
    bf16x8 ahi[4], alo[4];
    #pragma unroll
    for (int t = 0; t < 4; ++t){
      int arow = wrow0 + t*16 + lrow; if (arow > M-1) arow = M-1;
      const float* ap = Xm + (size_t)arow*DH + kk;
      float4 a0 = ((const float4*)ap)[0];
      float4 a1 = ((const float4*)ap)[1];
      float av[8] = {a0.x,a0.y,a0.z,a0.w,a1.x,a1.y,a1.z,a1.w};
      #pragma unroll
      for (int j = 0; j < 8; ++j){
        short h, l; split_bf(av[j], h, l);
        ahi[t][j] = h; alo[t][j] = l;
      }
    }
    #pragma unroll
    for (int n0 = 0; n0 < 8; ++n0){
      int f = (n0*KS + ks)*64 + lane;
      bf16x8 bhi = wp[f*2];
      bf16x8 blo = wp[f*2 + 1];
      #pragma unroll
      for (int t = 0; t < 4; ++t){
        acc[n0][t] = __builtin_amdgcn_mfma_f32_16x16x32_bf16(ahi[t], bhi, acc[n0][t], 0, 0, 0);
        acc[n0][t] = __builtin_amdgcn_mfma_f32_16x16x32_bf16(alo[t], bhi, acc[n0][t], 0, 0, 0);
        acc[n0][t] = __builtin_amdgcn_mfma_f32_16x16x32_bf16(ahi[t], blo, acc[n0][t], 0, 0, 0);
      }
    }
  }
  #pragma unroll
  for (int n0 = 0; n0 < 8; ++n0){
    int col = n0*16 + lrow;
    float cb = cvec[col];
    #pragma unroll
    for (int t = 0; t < 4; ++t){
      #pragma unroll
      for (int r = 0; r < 4; ++r){
        int row = wrow0 + t*16 + quad*4 + r;
        if (row < M) Out[(size_t)row*DH + col] = acc[n0][t][r] + cb;
      }
    }
  }
}

// ---------------- BatchNorm (training stats) + LeakyReLU ----------------
__global__ __launch_bounds__(256) void k_bn_stats(const float* __restrict__ X, int N,
                                                  float* __restrict__ sums){
  __shared__ float acc[256];
  int tid = threadIdx.x;
  acc[tid] = 0.f;
  __syncthreads();
  int c4 = (tid & 31)*4;
  int rl = tid >> 5;
  float s0=0,s1=0,s2=0,s3=0,q0=0,q1=0,q2=0,q3=0;
  for (int r = blockIdx.x*8 + rl; r < N; r += gridDim.x*8){
    float4 v = *(const float4*)(X + (size_t)r*DH + c4);
    s0 += v.x; s1 += v.y; s2 += v.z; s3 += v.w;
    q0 += v.x*v.x; q1 += v.y*v.y; q2 += v.z*v.z; q3 += v.w*v.w;
  }
  atomicAdd(&acc[c4+0], s0);       atomicAdd(&acc[c4+1], s1);
  atomicAdd(&acc[c4+2], s2);       atomicAdd(&acc[c4+3], s3);
  atomicAdd(&acc[128+c4+0], q0);   atomicAdd(&acc[128+c4+1], q1);
  atomicAdd(&acc[128+c4+2], q2);   atomicAdd(&acc[128+c4+3], q3);
  __syncthreads();
  atomicAdd(&sums[tid], acc[tid]);
}

__global__ __launch_bounds__(256) void k_bn_apply(const float* __restrict__ X,
    const float* __restrict__ sums, const float* __restrict__ gamma, const float* __restrict__ beta,
    float* __restrict__ Y, int total4, float invN){
  __shared__ float sc[128], sb[128];
  int tid = threadIdx.x;
  if (tid < 128){
    float m = sums[tid]*invN;
    float v = sums[128 + tid]*invN - m*m;
    float s = rsqrtf(v + 1e-5f) * gamma[tid];
    sc[tid] = s;
    sb[tid] = beta[tid] - m*s;
  }
  __syncthreads();
  for (int idx = blockIdx.x*blockDim.x + tid; idx < total4; idx += gridDim.x*blockDim.x){
    float4 v = ((const float4*)X)[idx];
    int c = (idx & 31)*4;
    float y0 = v.x*sc[c+0] + sb[c+0];
    float y1 = v.y*sc[c+1] + sb[c+1];
    float y2 = v.z*sc[c+2] + sb[c+2];
    float y3 = v.w*sc[c+3] + sb[c+3];
    float4 o;
    o.x = y0 >= 0.f ? y0 : 0.01f*y0;
    o.y = y1 >= 0.f ? y1 : 0.01f*y1;
    o.z = y2 >= 0.f ? y2 : 0.01f*y2;
    o.w = y3 >= 0.f ? y3 : 0.01f*y3;
    ((float4*)Y)[idx] = o;
  }
}

// ---------------- decoder (half-wave per label edge, float4) ----------------
__global__ __launch_bounds__(256) void k_decode(const float* __restrict__ G, const float* __restrict__ Dd,
    const int* __restrict__ ls, const int* __restrict__ ld, float* __restrict__ out, int E){
  int w = (blockIdx.x*blockDim.x + threadIdx.x) >> 5;
  int lane = threadIdx.x & 31;
  if (w >= E) return;
  int a = ls[w], b = ld[w];
  float4 g = *(const float4*)(G  + (size_t)a*DH + lane*4);
  float4 d = *(const float4*)(Dd + (size_t)b*DH + lane*4);
  float s = g.x*d.x + g.y*d.y + g.z*d.z + g.w*d.w;
  #pragma unroll
  for (int off = 16; off; off >>= 1) s += __shfl_down(s, off, 32);
  if (lane == 0) out[w] = s;
}

// ---------------- launch ----------------
extern "C" void kernel_launch(void* const* d_in, const int* in_sizes, int n_in,
                              void* d_out, int out_size, void* d_ws, size_t ws_size,
                              hipStream_t stream){
  const float* x_gene = (const float*)d_in[0];
  const float* x_dis  = (const float*)d_in[1];
  const float* Wd1 = (const float*)d_in[2];
  const float* Ws1 = (const float*)d_in[3];
  const float* Wu1 = (const float*)d_in[4];
  const float* bd1 = (const float*)d_in[5];
  const float* bs1 = (const float*)d_in[6];
  const float* bu1 = (const float*)d_in[7];
  const float* Wd2 = (const float*)d_in[8];
  const float* Ws2 = (const float*)d_in[9];
  const float* Wu2 = (const float*)d_in[10];
  const float* bd2 = (const float*)d_in[11];
  const float* bs2 = (const float*)d_in[12];
  const float* bu2 = (const float*)d_in[13];
  const float* bng = (const float*)d_in[14];
  const float* bnb = (const float*)d_in[15];
  const int* gg_src  = (const int*)d_in[16];
  const int* gg_dst  = (const int*)d_in[17];
  const int* gda_src = (const int*)d_in[18];
  const int* gda_dst = (const int*)d_in[19];
  const int* lsrc = (const int*)d_in[20];
  const int* ldst = (const int*)d_in[21];

  char* ws = (char*)d_ws;
  size_t off = 0;
  auto alloc = [&](size_t bytes)->void*{
    void* p = ws + off; off += (bytes + 255) & ~(size_t)255; return p;
  };
  int* gg_ptr  = (int*)alloc((NG+1)*4);
  int* gg_col  = (int*)alloc((size_t)EGG*4);
  int* gda_ptr = (int*)alloc((ND+1)*4);
  int* gda_col = (int*)alloc((size_t)EGDA*4);
  int* rev_ptr = (int*)alloc((NG+1)*4);
  int* rev_col = (int*)alloc((size_t)EGDA*4);
  int* tmp     = (int*)alloc((size_t)NG*4);
  float* AB1 = (float*)alloc(6*16384*4);
  float* AB2 = (float*)alloc(6*16384*4);
  float* cv1 = (float*)alloc(3*128*4);
  float* cv2 = (float*)alloc(3*128*4);
  float* cg1 = (float*)alloc(128*4);
  float* cd1 = (float*)alloc(128*4);
  float* cg2 = (float*)alloc(128*4);
  float* cd2 = (float*)alloc(128*4);
  bf16* Wg1  = (bf16*)alloc(98304*2);
  bf16* Wp1  = (bf16*)alloc(65536*2);
  bf16* Wg2  = (bf16*)alloc(98304*2);
  bf16* Wp2  = (bf16*)alloc(65536*2);
  float* aggGG  = (float*)alloc((size_t)NG*DH*4);
  float* aggREV = (float*)alloc((size_t)NG*DH*4);
  float* aggGDA = (float*)alloc((size_t)ND*DH*4);
  float* Xg2 = (float*)alloc((size_t)NG*DH*4);
  float* Xd2 = (float*)alloc((size_t)ND*DH*4);
  float* outg = (float*)alloc((size_t)NG*DH*4);
  float* outd = (float*)alloc((size_t)ND*DH*4);
  float* bnsum = (float*)alloc(2*256*4);

  // --- CSR: gene->gene grouped by gg_dst ---
  hipMemsetAsync(tmp, 0, NG*4, stream);
  k_count<<<512,256,0,stream>>>(gg_dst, EGG, tmp);
  k_exscan<<<1,1024,0,stream>>>(tmp, gg_ptr, NG);
  k_copy_int<<<(NG+255)/256,256,0,stream>>>(gg_ptr, tmp, NG);
  k_fill<<<512,256,0,stream>>>(gg_dst, gg_src, EGG, tmp, gg_col);
  // --- CSR: gene->disease grouped by gda_dst ---
  hipMemsetAsync(tmp, 0, ND*4, stream);
  k_count<<<512,256,0,stream>>>(gda_dst, EGDA, tmp);
  k_exscan<<<1,1024,0,stream>>>(tmp, gda_ptr, ND);
  k_copy_int<<<(ND+255)/256,256,0,stream>>>(gda_ptr, tmp, ND);
  k_fill<<<512,256,0,stream>>>(gda_dst, gda_src, EGDA, tmp, gda_col);
  // --- CSR: disease->gene (reverse) grouped by gda_src ---
  hipMemsetAsync(tmp, 0, NG*4, stream);
  k_count<<<512,256,0,stream>>>(gda_src, EGDA, tmp);
  k_exscan<<<1,1024,0,stream>>>(tmp, rev_ptr, NG);
  k_copy_int<<<(NG+255)/256,256,0,stream>>>(rev_ptr, tmp, NG);
  k_fill<<<512,256,0,stream>>>(gda_src, gda_dst, EGDA, tmp, rev_col);

  // --- composed weights (both layers) ---
  k_compose_AB<<<384,256,0,stream>>>(Wd1, Ws1, Wu1, AB1);
  k_compose_AB<<<384,256,0,stream>>>(Wd2, Ws2, Wu2, AB2);
  k_compose_bias<<<2,256,0,stream>>>(bd1, bs1, bu1, Wu1, cv1);
  k_compose_bias<<<2,256,0,stream>>>(bd2, bs2, bu2, Wu2, cv2);
  k_pack_gene<<<192,256,0,stream>>>(AB1, cv1, Wg1, cg1);
  k_pack_gene<<<192,256,0,stream>>>(AB2, cv2, Wg2, cg2);
  k_pack_dis<<<128,256,0,stream>>>(AB1, cv1, Wp1, cd1);
  k_pack_dis<<<128,256,0,stream>>>(AB2, cv2, Wp2, cd2);

  // --- layer 1 ---
  k_agg_mean<<<(NG*32+255)/256,256,0,stream>>>(x_gene, gg_ptr, gg_col, aggGG, NG);
  k_agg_mean<<<(ND*32+255)/256,256,0,stream>>>(x_gene, gda_ptr, gda_col, aggGDA, ND);
  k_agg_mean<<<(NG*32+255)/256,256,0,stream>>>(x_dis, rev_ptr, rev_col, aggREV, NG);
  k_gemm_cat<<<(NG+255)/256,256,0,stream>>>(x_gene, aggGG, aggREV, Wg1, cg1, outg, NG, 12);
  k_gemm_cat<<<(ND+255)/256,256,0,stream>>>(x_dis, aggGDA, aggGDA, Wp1, cd1, outd, ND, 8);
  hipMemsetAsync(bnsum, 0, 2*256*4, stream);
  k_bn_stats<<<256,256,0,stream>>>(outg, NG, bnsum);
  k_bn_stats<<<256,256,0,stream>>>(outd, ND, bnsum + 256);
  k_bn_apply<<<1024,256,0,stream>>>(outg, bnsum, bng, bnb, Xg2, NG*DH/4, 1.f/NG);
  k_bn_apply<<<1024,256,0,stream>>>(outd, bnsum + 256, bng + 128, bnb + 128, Xd2, ND*DH/4, 1.f/ND);

  // --- layer 2 ---
  k_agg_mean<<<(NG*32+255)/256,256,0,stream>>>(Xg2, gg_ptr, gg_col, aggGG, NG);
  k_agg_mean<<<(ND*32+255)/256,256,0,stream>>>(Xg2, gda_ptr, gda_col, aggGDA, ND);
  k_agg_mean<<<(NG*32+255)/256,256,0,stream>>>(Xd2, rev_ptr, rev_col, aggREV, NG);
  k_gemm_cat<<<(NG+255)/256,256,0,stream>>>(Xg2, aggGG, aggREV, Wg2, cg2, outg, NG, 12);
  k_gemm_cat<<<(ND+255)/256,256,0,stream>>>(Xd2, aggGDA, aggGDA, Wp2, cd2, outd, ND, 8);

  // --- decoder ---
  k_decode<<<(ELAB*32+255)/256,256,0,stream>>>(outg, outd, lsrc, ldst, (float*)d_out, ELAB);
}

// Round 4
// 664.857 us; speedup vs baseline: 1.7740x; 1.4131x over previous
//
#include <hip/hip_runtime.h>
#include <hip/hip_bf16.h>
#include <cstddef>

#define NG   50000
#define ND   20000
#define DH   128
#define EGG  800000
#define EGDA 400000
#define ELAB 200000

typedef __hip_bfloat16  bf16;
typedef __attribute__((ext_vector_type(8))) short bf16x8;
typedef __attribute__((ext_vector_type(4))) float f32x4;

__device__ __forceinline__ float bf2f(short s){
  return __uint_as_float(((unsigned)(unsigned short)s) << 16);
}
__device__ __forceinline__ unsigned short f2b(float x){
  unsigned u = __float_as_uint(x);
  return (unsigned short)((u + 0x7FFF + ((u >> 16) & 1)) >> 16);
}
// split float into hi/lo bf16 bit-patterns (truncation; x - hi is exact)
__device__ __forceinline__ void split_bf(float x, short& h, short& l){
  unsigned u = __float_as_uint(x);
  h = (short)(u >> 16);
  float r = x - __uint_as_float(u & 0xFFFF0000u);
  l = (short)(__float_as_uint(r) >> 16);
}

// ---------------- CSR build: two-level counting sort ----------------
// buckets of 128 dst each; B1 = ceil(N/128)

__global__ __launch_bounds__(256) void k_hist1(const int* __restrict__ key, int n,
                                               int* __restrict__ hist, int B1){
  __shared__ int lh[400];
  for (int t = threadIdx.x; t < B1; t += 256) lh[t] = 0;
  __syncthreads();
  for (int i = blockIdx.x*blockDim.x + threadIdx.x; i < n; i += gridDim.x*blockDim.x)
    atomicAdd(&lh[key[i] >> 7], 1);
  __syncthreads();
  for (int t = threadIdx.x; t < B1; t += 256){
    int c = lh[t];
    if (c) atomicAdd(&hist[t], c);
  }
}

// n multiple of 4; writes exclusive scan to ptr (and ptr[n]=total) and to cur
__global__ __launch_bounds__(1024) void k_exscan(const int* __restrict__ cnt,
                                                 int* __restrict__ ptr, int* __restrict__ cur, int n){
  __shared__ int wsum[16];
  __shared__ int carry;
  const int tid = threadIdx.x, lane = tid & 63, wid = tid >> 6;
  if (tid == 0) carry = 0;
  __syncthreads();
  for (int base = 0; base < n; base += 4096){
    int i0 = base + tid*4;
    int4 v = {0,0,0,0};
    if (i0 < n) v = *(const int4*)(cnt + i0);
    int tsum = v.x + v.y + v.z + v.w;
    int x = tsum;
    #pragma unroll
    for (int off = 1; off < 64; off <<= 1){
      int t = __shfl_up(x, off);
      if (lane >= off) x += t;
    }
    if (lane == 63) wsum[wid] = x;
    __syncthreads();
    if (wid == 0 && lane < 16){
      int w = wsum[lane];
      #pragma unroll
      for (int off = 1; off < 16; off <<= 1){
        int t = __shfl_up(w, off);
        if (lane >= off) w += t;
      }
      wsum[lane] = w;
    }
    __syncthreads();
    int waveoff = wid ? wsum[wid-1] : 0;
    if (i0 < n){
      int ex = carry + waveoff + x - tsum;
      int4 o;
      o.x = ex; o.y = ex + v.x; o.z = o.y + v.y; o.w = o.z + v.z;
      *(int4*)(ptr + i0) = o;
      *(int4*)(cur + i0) = o;
    }
    int total = wsum[15];
    __syncthreads();
    if (tid == 0) carry += total;
    __syncthreads();
  }
  if (tid == 0) ptr[n] = carry;
}

// scatter edges into coarse buckets as packed (dstLocal<<17 | src)
__global__ __launch_bounds__(256) void k_scatter1(const int* __restrict__ key, const int* __restrict__ val,
                                                  int n, int* __restrict__ gcur,
                                                  unsigned* __restrict__ pk, int B1){
  __shared__ int lh[400];
  __shared__ int base[400];
  const int tid = threadIdx.x;
  const int chunk0 = blockIdx.x*4096;
  for (int t = tid; t < B1; t += 256) lh[t] = 0;
  __syncthreads();
  int kd[16], vv[16];
  #pragma unroll
  for (int it = 0; it < 16; ++it){
    int i = chunk0 + it*256 + tid;
    int k = -1, v = 0;
    if (i < n){ k = key[i]; v = val[i]; atomicAdd(&lh[k >> 7], 1); }
    kd[it] = k; vv[it] = v;
  }
  __syncthreads();
  for (int t = tid; t < B1; t += 256){
    int c = lh[t];
    base[t] = c ? atomicAdd(&gcur[t], c) : 0;
    lh[t] = 0;
  }
  __syncthreads();
  #pragma unroll
  for (int it = 0; it < 16; ++it){
    int k = kd[it];
    if (k >= 0){
      int b = k >> 7;
      int p = base[b] + atomicAdd(&lh[b], 1);
      pk[p] = ((unsigned)(k & 127) << 17) | (unsigned)vv[it];
    }
  }
}

// per-bucket fine CSR: write ptr + col
__global__ __launch_bounds__(256) void k_csr2(const unsigned* __restrict__ pk,
                                              const int* __restrict__ gbase,
                                              int* __restrict__ ptr, int* __restrict__ col,
                                              int N, int B1){
  __shared__ int lh[128];
  __shared__ int cur[128];
  __shared__ int sh0;
  const int b = blockIdx.x, tid = threadIdx.x;
  const int s = gbase[b], e = gbase[b+1];
  if (tid < 128) lh[tid] = 0;
  __syncthreads();
  for (int i = s + tid; i < e; i += 256)
    atomicAdd(&lh[(pk[i] >> 17) & 127], 1);
  __syncthreads();
  int lane = tid & 63;
  int v = 0, x = 0;
  if (tid < 128){
    v = lh[tid]; x = v;
    #pragma unroll
    for (int o = 1; o < 64; o <<= 1){
      int t = __shfl_up(x, o);
      if (lane >= o) x += t;
    }
    if (tid == 63) sh0 = x;
  }
  __syncthreads();
  if (tid < 128){
    int excl = x - v + (tid >= 64 ? sh0 : 0);
    cur[tid] = s + excl;
    int g = (b << 7) + tid;
    if (g < N) ptr[g] = s + excl;
  }
  __syncthreads();
  for (int i = s + tid; i < e; i += 256){
    unsigned p = pk[i];
    int dl = (p >> 17) & 127;
    int pos = atomicAdd(&cur[dl], 1);
    col[pos] = (int)(p & 0x1FFFFu);
  }
  if (b == 0 && tid == 0) ptr[N] = gbase[B1];
}

// ---------------- weight composition (fp32) ----------------
__global__ void k_compose_AB(const float* __restrict__ Wd, const float* __restrict__ Ws,
                             const float* __restrict__ Wu, float* __restrict__ AB){
  int idx = blockIdx.x*256 + threadIdx.x;      // 6*16384
  int mat = idx >> 14;
  int r   = (idx >> 7) & 127;
  int c   = idx & 127;
  int i   = mat >> 1;
  int isB = mat & 1;
  const float* P = (isB ? Ws : Wd) + i*16384 + r*128;
  const float* Q = Wu + i*32768 + (isB ? 16384 : 0) + c;
  float s = 0.f;
  for (int h = 0; h < 128; ++h) s += P[h] * Q[h*128];
  AB[idx] = s;
}

__global__ void k_compose_bias(const float* __restrict__ bd, const float* __restrict__ bs,
                               const float* __restrict__ bu, const float* __restrict__ Wu,
                               float* __restrict__ cv){
  int idx = blockIdx.x*256 + threadIdx.x;      // 3*128
  if (idx >= 384) return;
  int i = idx >> 7, h = idx & 127;
  float s = bu[i*128 + h];
  const float* Ut = Wu + i*32768 + h;
  const float* Ub = Ut + 16384;
  for (int k = 0; k < 128; ++k)
    s += bd[i*128 + k] * Ut[k*128] + bs[i*128 + k] * Ub[k*128];
  cv[idx] = s;
}

// pack B-fragment order, hi/lo interleaved per fragment
__global__ void k_pack_gene(const float* __restrict__ AB, const float* __restrict__ cv,
                            bf16* __restrict__ Wp, float* __restrict__ cg){
  int idx = blockIdx.x*256 + threadIdx.x;      // 8*12*512 = 49152
  int n0  = idx / 6144;
  int rem = idx - n0*6144;
  int ks  = rem >> 9;
  int lane = (rem >> 3) & 63;
  int j   = rem & 7;
  int k   = ks*32 + (lane >> 4)*8 + j;
  int col = n0*16 + (lane & 15);
  float v;
  if      (k < 128) v = 0.5f*(AB[0*16384 + k*128 + col] + AB[4*16384 + k*128 + col]);
  else if (k < 256) v = 0.5f* AB[1*16384 + (k-128)*128 + col];
  else              v = 0.5f* AB[5*16384 + (k-256)*128 + col];
  short h, l; split_bf(v, h, l);
  int f = idx >> 3;
  ((short*)Wp)[f*16 + j]     = h;
  ((short*)Wp)[f*16 + 8 + j] = l;
  if (idx < 128) cg[idx] = 0.5f*(cv[idx] + cv[256 + idx]);
}

__global__ void k_pack_dis(const float* __restrict__ AB, const float* __restrict__ cv,
                           bf16* __restrict__ Wp, float* __restrict__ cd){
  int idx = blockIdx.x*256 + threadIdx.x;      // 8*8*512 = 32768
  int n0  = idx >> 12;
  int ks  = (idx >> 9) & 7;
  int lane = (idx >> 3) & 63;
  int j   = idx & 7;
  int k   = ks*32 + (lane >> 4)*8 + j;
  int col = n0*16 + (lane & 15);
  float v = (k < 128) ? AB[2*16384 + k*128 + col] : AB[3*16384 + (k-128)*128 + col];
  short h, l; split_bf(v, h, l);
  int f = idx >> 3;
  ((short*)Wp)[f*16 + j]     = h;
  ((short*)Wp)[f*16 + 8 + j] = l;
  if (idx < 128) cd[idx] = cv[128 + idx];
}

// ---------------- fp32 -> bf16 table conversion ----------------
__global__ __launch_bounds__(256) void k_f2b(const float* __restrict__ X,
                                             unsigned short* __restrict__ Y, int n4){
  int idx = blockIdx.x*256 + threadIdx.x;
  if (idx >= n4) return;
  float4 v = ((const float4*)X)[idx];
  ushort4 o;
  o.x = f2b(v.x); o.y = f2b(v.y); o.z = f2b(v.z); o.w = f2b(v.w);
  ((ushort4*)Y)[idx] = o;
}

// ---------------- mean aggregation (quarter-wave per dst, bf16 in/out) ----------------
__global__ __launch_bounds__(256) void k_agg16(const bf16* __restrict__ Xb,
    const int* __restrict__ ptr, const int* __restrict__ col,
    bf16* __restrict__ Out, int N){
  int q = (blockIdx.x*256 + threadIdx.x) >> 4;
  int lane = threadIdx.x & 15;
  if (q >= N) return;
  int s = ptr[q], e = ptr[q+1];
  float a[8];
  #pragma unroll
  for (int j = 0; j < 8; ++j) a[j] = 0.f;
  for (int i = s; i < e; ++i){
    int src = col[i];
    bf16x8 v = *(const bf16x8*)(Xb + (size_t)src*DH + lane*8);
    #pragma unroll
    for (int j = 0; j < 8; ++j) a[j] += bf2f(v[j]);
  }
  float inv = 1.f / fmaxf((float)(e - s), 1.f);
  bf16x8 o;
  #pragma unroll
  for (int j = 0; j < 8; ++j) o[j] = (short)f2b(a[j]*inv);
  *(bf16x8*)(Out + (size_t)q*DH + lane*8) = o;
}

// ---------------- concat-K MFMA GEMM (bf16 A, split-bf16 B, 64 rows/wave) ----------------
__global__ __launch_bounds__(256) void k_gemm_cat(
    const bf16* __restrict__ X0, const bf16* __restrict__ X1, const bf16* __restrict__ X2,
    const bf16* __restrict__ Wp, const float* __restrict__ cvec,
    float* __restrict__ Out, int M, int KS){
  const int wave = threadIdx.x >> 6;
  const int lane = threadIdx.x & 63;
  const int lrow = lane & 15, quad = lane >> 4;
  const int wrow0 = blockIdx.x*256 + wave*64;
  const bf16* Xs[3] = {X0, X1, X2};
  f32x4 acc[8][4];
  #pragma unroll
  for (int i = 0; i < 8; ++i)
    #pragma unroll
    for (int t = 0; t < 4; ++t) acc[i][t] = 0.0f;
  const bf16x8* wp = (const bf16x8*)Wp;
  for (int ks = 0; ks < KS; ++ks){
    const bf16* Xm = Xs[ks >> 2];
    int kk = (ks & 3)*32 + quad*8;
    bf16x8 a[4];
    #pragma unroll
    for (int t = 0; t < 4; ++t){
      int arow = wrow0 + t*16 + lrow; if (arow > M-1) arow = M-1;
      a[t] = *(const bf16x8*)(Xm + (size_t)arow*DH + kk);
    }
    #pragma unroll
    for (int n0 = 0; n0 < 8; ++n0){
      int f = (n0*KS + ks)*64 + lane;
      bf16x8 bhi = wp[f*2];
      bf16x8 blo = wp[f*2 + 1];
      #pragma unroll
      for (int t = 0; t < 4; ++t){
        acc[n0][t] = __builtin_amdgcn_mfma_f32_16x16x32_bf16(a[t], bhi, acc[n0][t], 0, 0, 0);
        acc[n0][t] = __builtin_amdgcn_mfma_f32_16x16x32_bf16(a[t], blo, acc[n0][t], 0, 0, 0);
      }
    }
  }
  #pragma unroll
  for (int n0 = 0; n0 < 8; ++n0){
    int col = n0*16 + lrow;
    float cb = cvec[col];
    #pragma unroll
    for (int t = 0; t < 4; ++t){
      #pragma unroll
      for (int r = 0; r < 4; ++r){
        int row = wrow0 + t*16 + quad*4 + r;
        if (row < M) Out[(size_t)row*DH + col] = acc[n0][t][r] + cb;
      }
    }
  }
}

// ---------------- BatchNorm (training stats) + LeakyReLU ----------------
__global__ __launch_bounds__(256) void k_bn_stats(const float* __restrict__ X, int N,
                                                  float* __restrict__ sums){
  __shared__ float acc[256];
  int tid = threadIdx.x;
  acc[tid] = 0.f;
  __syncthreads();
  int c4 = (tid & 31)*4;
  int rl = tid >> 5;
  float s0=0,s1=0,s2=0,s3=0,q0=0,q1=0,q2=0,q3=0;
  for (int r = blockIdx.x*8 + rl; r < N; r += gridDim.x*8){
    float4 v = *(const float4*)(X + (size_t)r*DH + c4);
    s0 += v.x; s1 += v.y; s2 += v.z; s3 += v.w;
    q0 += v.x*v.x; q1 += v.y*v.y; q2 += v.z*v.z; q3 += v.w*v.w;
  }
  atomicAdd(&acc[c4+0], s0);       atomicAdd(&acc[c4+1], s1);
  atomicAdd(&acc[c4+2], s2);       atomicAdd(&acc[c4+3], s3);
  atomicAdd(&acc[128+c4+0], q0);   atomicAdd(&acc[128+c4+1], q1);
  atomicAdd(&acc[128+c4+2], q2);   atomicAdd(&acc[128+c4+3], q3);
  __syncthreads();
  atomicAdd(&sums[tid], acc[tid]);
}

// BN + LeakyReLU, bf16 output (feeds layer-2 aggregation and GEMM A)
__global__ __launch_bounds__(256) void k_bn_apply(const float* __restrict__ X,
    const float* __restrict__ sums, const float* __restrict__ gamma, const float* __restrict__ beta,
    unsigned short* __restrict__ Yb, int total4, float invN){
  __shared__ float sc[128], sb[128];
  int tid = threadIdx.x;
  if (tid < 128){
    float m = sums[tid]*invN;
    float v = sums[128 + tid]*invN - m*m;
    float s = rsqrtf(v + 1e-5f) * gamma[tid];
    sc[tid] = s;
    sb[tid] = beta[tid] - m*s;
  }
  __syncthreads();
  for (int idx = blockIdx.x*blockDim.x + tid; idx < total4; idx += gridDim.x*blockDim.x){
    float4 v = ((const float4*)X)[idx];
    int c = (idx & 31)*4;
    float y0 = v.x*sc[c+0] + sb[c+0];
    float y1 = v.y*sc[c+1] + sb[c+1];
    float y2 = v.z*sc[c+2] + sb[c+2];
    float y3 = v.w*sc[c+3] + sb[c+3];
    y0 = y0 >= 0.f ? y0 : 0.01f*y0;
    y1 = y1 >= 0.f ? y1 : 0.01f*y1;
    y2 = y2 >= 0.f ? y2 : 0.01f*y2;
    y3 = y3 >= 0.f ? y3 : 0.01f*y3;
    ushort4 o;
    o.x = f2b(y0); o.y = f2b(y1); o.z = f2b(y2); o.w = f2b(y3);
    ((ushort4*)Yb)[idx] = o;
  }
}

// ---------------- decoder (half-wave per label edge, fp32) ----------------
__global__ __launch_bounds__(256) void k_decode(const float* __restrict__ G, const float* __restrict__ Dd,
    const int* __restrict__ ls, const int* __restrict__ ld, float* __restrict__ out, int E){
  int w = (blockIdx.x*blockDim.x + threadIdx.x) >> 5;
  int lane = threadIdx.x & 31;
  if (w >= E) return;
  int a = ls[w], b = ld[w];
  float4 g = *(const float4*)(G  + (size_t)a*DH + lane*4);
  float4 d = *(const float4*)(Dd + (size_t)b*DH + lane*4);
  float s = g.x*d.x + g.y*d.y + g.z*d.z + g.w*d.w;
  #pragma unroll
  for (int off = 16; off; off >>= 1) s += __shfl_down(s, off, 32);
  if (lane == 0) out[w] = s;
}

// ---------------- launch ----------------
extern "C" void kernel_launch(void* const* d_in, const int* in_sizes, int n_in,
                              void* d_out, int out_size, void* d_ws, size_t ws_size,
                              hipStream_t stream){
  const float* x_gene = (const float*)d_in[0];
  const float* x_dis  = (const float*)d_in[1];
  const float* Wd1 = (const float*)d_in[2];
  const float* Ws1 = (const float*)d_in[3];
  const float* Wu1 = (const float*)d_in[4];
  const float* bd1 = (const float*)d_in[5];
  const float* bs1 = (const float*)d_in[6];
  const float* bu1 = (const float*)d_in[7];
  const float* Wd2 = (const float*)d_in[8];
  const float* Ws2 = (const float*)d_in[9];
  const float* Wu2 = (const float*)d_in[10];
  const float* bd2 = (const float*)d_in[11];
  const float* bs2 = (const float*)d_in[12];
  const float* bu2 = (const float*)d_in[13];
  const float* bng = (const float*)d_in[14];
  const float* bnb = (const float*)d_in[15];
  const int* gg_src  = (const int*)d_in[16];
  const int* gg_dst  = (const int*)d_in[17];
  const int* gda_src = (const int*)d_in[18];
  const int* gda_dst = (const int*)d_in[19];
  const int* lsrc = (const int*)d_in[20];
  const int* ldst = (const int*)d_in[21];

  char* ws = (char*)d_ws;
  size_t off = 0;
  auto alloc = [&](size_t bytes)->void*{
    void* p = ws + off; off += (bytes + 255) & ~(size_t)255; return p;
  };
  int* gg_ptr  = (int*)alloc((NG+2)*4);
  int* gg_col  = (int*)alloc((size_t)EGG*4);
  int* gda_ptr = (int*)alloc((ND+2)*4);
  int* gda_col = (int*)alloc((size_t)EGDA*4);
  int* rev_ptr = (int*)alloc((NG+2)*4);
  int* rev_col = (int*)alloc((size_t)EGDA*4);
  int* hist    = (int*)alloc(400*4);
  int* gbase   = (int*)alloc(400*4);
  int* gcur    = (int*)alloc(400*4);
  unsigned* pk = (unsigned*)alloc((size_t)EGG*4);
  float* AB1 = (float*)alloc(6*16384*4);
  float* AB2 = (float*)alloc(6*16384*4);
  float* cv1 = (float*)alloc(3*128*4);
  float* cv2 = (float*)alloc(3*128*4);
  float* cg1 = (float*)alloc(128*4);
  float* cd1 = (float*)alloc(128*4);
  float* cg2 = (float*)alloc(128*4);
  float* cd2 = (float*)alloc(128*4);
  bf16* Wg1  = (bf16*)alloc(98304*2);
  bf16* Wp1  = (bf16*)alloc(65536*2);
  bf16* Wg2  = (bf16*)alloc(98304*2);
  bf16* Wp2  = (bf16*)alloc(65536*2);
  bf16* xgb  = (bf16*)alloc((size_t)NG*DH*2);
  bf16* xdb  = (bf16*)alloc((size_t)ND*DH*2);
  bf16* aggGGb  = (bf16*)alloc((size_t)NG*DH*2);
  bf16* aggREVb = (bf16*)alloc((size_t)NG*DH*2);
  bf16* aggGDAb = (bf16*)alloc((size_t)ND*DH*2);
  bf16* Xg2b = (bf16*)alloc((size_t)NG*DH*2);
  bf16* Xd2b = (bf16*)alloc((size_t)ND*DH*2);
  float* outg = (float*)alloc((size_t)NG*DH*4);
  float* outd = (float*)alloc((size_t)ND*DH*4);
  float* bnsum = (float*)alloc(2*256*4);

  const int B1G = 391, B1Gp = 392;   // gene-dst buckets (NG/128)
  const int B1D = 157, B1Dp = 160;   // disease-dst buckets (ND/128)

  // --- CSR: gene->gene grouped by gg_dst ---
  hipMemsetAsync(hist, 0, B1Gp*4, stream);
  k_hist1<<<256,256,0,stream>>>(gg_dst, EGG, hist, B1G);
  k_exscan<<<1,1024,0,stream>>>(hist, gbase, gcur, B1Gp);
  k_scatter1<<<(EGG+4095)/4096,256,0,stream>>>(gg_dst, gg_src, EGG, gcur, pk, B1G);
  k_csr2<<<B1G,256,0,stream>>>(pk, gbase, gg_ptr, gg_col, NG, B1G);
  // --- CSR: gene->disease grouped by gda_dst ---
  hipMemsetAsync(hist, 0, B1Dp*4, stream);
  k_hist1<<<256,256,0,stream>>>(gda_dst, EGDA, hist, B1D);
  k_exscan<<<1,1024,0,stream>>>(hist, gbase, gcur, B1Dp);
  k_scatter1<<<(EGDA+4095)/4096,256,0,stream>>>(gda_dst, gda_src, EGDA, gcur, pk, B1D);
  k_csr2<<<B1D,256,0,stream>>>(pk, gbase, gda_ptr, gda_col, ND, B1D);
  // --- CSR: disease->gene (reverse) grouped by gda_src ---
  hipMemsetAsync(hist, 0, B1Gp*4, stream);
  k_hist1<<<256,256,0,stream>>>(gda_src, EGDA, hist, B1G);
  k_exscan<<<1,1024,0,stream>>>(hist, gbase, gcur, B1Gp);
  k_scatter1<<<(EGDA+4095)/4096,256,0,stream>>>(gda_src, gda_dst, EGDA, gcur, pk, B1G);
  k_csr2<<<B1G,256,0,stream>>>(pk, gbase, rev_ptr, rev_col, NG, B1G);

  // --- composed weights (both layers) ---
  k_compose_AB<<<384,256,0,stream>>>(Wd1, Ws1, Wu1, AB1);
  k_compose_AB<<<384,256,0,stream>>>(Wd2, Ws2, Wu2, AB2);
  k_compose_bias<<<2,256,0,stream>>>(bd1, bs1, bu1, Wu1, cv1);
  k_compose_bias<<<2,256,0,stream>>>(bd2, bs2, bu2, Wu2, cv2);
  k_pack_gene<<<192,256,0,stream>>>(AB1, cv1, Wg1, cg1);
  k_pack_gene<<<192,256,0,stream>>>(AB2, cv2, Wg2, cg2);
  k_pack_dis<<<128,256,0,stream>>>(AB1, cv1, Wp1, cd1);
  k_pack_dis<<<128,256,0,stream>>>(AB2, cv2, Wp2, cd2);

  // --- bf16 feature tables ---
  k_f2b<<<(NG*DH/4+255)/256,256,0,stream>>>(x_gene, (unsigned short*)xgb, NG*DH/4);
  k_f2b<<<(ND*DH/4+255)/256,256,0,stream>>>(x_dis,  (unsigned short*)xdb, ND*DH/4);

  // --- layer 1 ---
  k_agg16<<<(NG*16+255)/256,256,0,stream>>>(xgb, gg_ptr, gg_col, aggGGb, NG);
  k_agg16<<<(ND*16+255)/256,256,0,stream>>>(xgb, gda_ptr, gda_col, aggGDAb, ND);
  k_agg16<<<(NG*16+255)/256,256,0,stream>>>(xdb, rev_ptr, rev_col, aggREVb, NG);
  k_gemm_cat<<<(NG+255)/256,256,0,stream>>>(xgb, aggGGb, aggREVb, Wg1, cg1, outg, NG, 12);
  k_gemm_cat<<<(ND+255)/256,256,0,stream>>>(xdb, aggGDAb, aggGDAb, Wp1, cd1, outd, ND, 8);
  hipMemsetAsync(bnsum, 0, 2*256*4, stream);
  k_bn_stats<<<256,256,0,stream>>>(outg, NG, bnsum);
  k_bn_stats<<<256,256,0,stream>>>(outd, ND, bnsum + 256);
  k_bn_apply<<<1024,256,0,stream>>>(outg, bnsum, bng, bnb, (unsigned short*)Xg2b, NG*DH/4, 1.f/NG);
  k_bn_apply<<<1024,256,0,stream>>>(outd, bnsum + 256, bng + 128, bnb + 128, (unsigned short*)Xd2b, ND*DH/4, 1.f/ND);

  // --- layer 2 ---
  k_agg16<<<(NG*16+255)/256,256,0,stream>>>(Xg2b, gg_ptr, gg_col, aggGGb, NG);
  k_agg16<<<(ND*16+255)/256,256,0,stream>>>(Xg2b, gda_ptr, gda_col, aggGDAb, ND);
  k_agg16<<<(NG*16+255)/256,256,0,stream>>>(Xd2b, rev_ptr, rev_col, aggREVb, NG);
  k_gemm_cat<<<(NG+255)/256,256,0,stream>>>(Xg2b, aggGGb, aggREVb, Wg2, cg2, outg, NG, 12);
  k_gemm_cat<<<(ND+255)/256,256,0,stream>>>(Xd2b, aggGDAb, aggGDAb, Wp2, cd2, outd, ND, 8);

  // --- decoder ---
  k_decode<<<(ELAB*32+255)/256,256,0,stream>>>(outg, outd, lsrc, ldst, (float*)d_out, ELAB);
}

// Round 5
// 581.141 us; speedup vs baseline: 2.0296x; 1.1441x over previous
//
#include <hip/hip_runtime.h>
#include <hip/hip_bf16.h>
#include <cstddef>

#define NG   50000
#define ND   20000
#define DH   128
#define EGG  800000
#define EGDA 400000
#define ELAB 200000

typedef __hip_bfloat16  bf16;
typedef __attribute__((ext_vector_type(8))) short bf16x8;
typedef __attribute__((ext_vector_type(4))) float f32x4;

__device__ __forceinline__ float bf2f(short s){
  return __uint_as_float(((unsigned)(unsigned short)s) << 16);
}
__device__ __forceinline__ unsigned short f2b(float x){
  unsigned u = __float_as_uint(x);
  return (unsigned short)((u + 0x7FFF + ((u >> 16) & 1)) >> 16);
}
// split float into hi/lo bf16 bit-patterns (truncation; x - hi is exact)
__device__ __forceinline__ void split_bf(float x, short& h, short& l){
  unsigned u = __float_as_uint(x);
  h = (short)(u >> 16);
  float r = x - __uint_as_float(u & 0xFFFF0000u);
  l = (short)(__float_as_uint(r) >> 16);
}

// ---------------- CSR build: two-level counting sort ----------------
__global__ __launch_bounds__(256) void k_hist1(const int* __restrict__ key, int n,
                                               int* __restrict__ hist, int B1){
  __shared__ int lh[400];
  for (int t = threadIdx.x; t < B1; t += 256) lh[t] = 0;
  __syncthreads();
  for (int i = blockIdx.x*blockDim.x + threadIdx.x; i < n; i += gridDim.x*blockDim.x)
    atomicAdd(&lh[key[i] >> 7], 1);
  __syncthreads();
  for (int t = threadIdx.x; t < B1; t += 256){
    int c = lh[t];
    if (c) atomicAdd(&hist[t], c);
  }
}

__global__ __launch_bounds__(1024) void k_exscan(const int* __restrict__ cnt,
                                                 int* __restrict__ ptr, int* __restrict__ cur, int n){
  __shared__ int wsum[16];
  __shared__ int carry;
  const int tid = threadIdx.x, lane = tid & 63, wid = tid >> 6;
  if (tid == 0) carry = 0;
  __syncthreads();
  for (int base = 0; base < n; base += 4096){
    int i0 = base + tid*4;
    int4 v = {0,0,0,0};
    if (i0 < n) v = *(const int4*)(cnt + i0);
    int tsum = v.x + v.y + v.z + v.w;
    int x = tsum;
    #pragma unroll
    for (int off = 1; off < 64; off <<= 1){
      int t = __shfl_up(x, off);
      if (lane >= off) x += t;
    }
    if (lane == 63) wsum[wid] = x;
    __syncthreads();
    if (wid == 0 && lane < 16){
      int w = wsum[lane];
      #pragma unroll
      for (int off = 1; off < 16; off <<= 1){
        int t = __shfl_up(w, off);
        if (lane >= off) w += t;
      }
      wsum[lane] = w;
    }
    __syncthreads();
    int waveoff = wid ? wsum[wid-1] : 0;
    if (i0 < n){
      int ex = carry + waveoff + x - tsum;
      int4 o;
      o.x = ex; o.y = ex + v.x; o.z = o.y + v.y; o.w = o.z + v.z;
      *(int4*)(ptr + i0) = o;
      *(int4*)(cur + i0) = o;
    }
    int total = wsum[15];
    __syncthreads();
    if (tid == 0) carry += total;
    __syncthreads();
  }
  if (tid == 0) ptr[n] = carry;
}

__global__ __launch_bounds__(256) void k_scatter1(const int* __restrict__ key, const int* __restrict__ val,
                                                  int n, int* __restrict__ gcur,
                                                  unsigned* __restrict__ pk, int B1){
  __shared__ int lh[400];
  __shared__ int base[400];
  const int tid = threadIdx.x;
  const int chunk0 = blockIdx.x*4096;
  for (int t = tid; t < B1; t += 256) lh[t] = 0;
  __syncthreads();
  int kd[16], vv[16];
  #pragma unroll
  for (int it = 0; it < 16; ++it){
    int i = chunk0 + it*256 + tid;
    int k = -1, v = 0;
    if (i < n){ k = key[i]; v = val[i]; atomicAdd(&lh[k >> 7], 1); }
    kd[it] = k; vv[it] = v;
  }
  __syncthreads();
  for (int t = tid; t < B1; t += 256){
    int c = lh[t];
    base[t] = c ? atomicAdd(&gcur[t], c) : 0;
    lh[t] = 0;
  }
  __syncthreads();
  #pragma unroll
  for (int it = 0; it < 16; ++it){
    int k = kd[it];
    if (k >= 0){
      int b = k >> 7;
      int p = base[b] + atomicAdd(&lh[b], 1);
      pk[p] = ((unsigned)(k & 127) << 17) | (unsigned)vv[it];
    }
  }
}

__global__ __launch_bounds__(256) void k_csr2(const unsigned* __restrict__ pk,
                                              const int* __restrict__ gbase,
                                              int* __restrict__ ptr, int* __restrict__ col,
                                              int N, int B1){
  __shared__ int lh[128];
  __shared__ int cur[128];
  __shared__ int sh0;
  const int b = blockIdx.x, tid = threadIdx.x;
  const int s = gbase[b], e = gbase[b+1];
  if (tid < 128) lh[tid] = 0;
  __syncthreads();
  for (int i = s + tid; i < e; i += 256)
    atomicAdd(&lh[(pk[i] >> 17) & 127], 1);
  __syncthreads();
  int lane = tid & 63;
  int v = 0, x = 0;
  if (tid < 128){
    v = lh[tid]; x = v;
    #pragma unroll
    for (int o = 1; o < 64; o <<= 1){
      int t = __shfl_up(x, o);
      if (lane >= o) x += t;
    }
    if (tid == 63) sh0 = x;
  }
  __syncthreads();
  if (tid < 128){
    int excl = x - v + (tid >= 64 ? sh0 : 0);
    cur[tid] = s + excl;
    int g = (b << 7) + tid;
    if (g < N) ptr[g] = s + excl;
  }
  __syncthreads();
  for (int i = s + tid; i < e; i += 256){
    unsigned p = pk[i];
    int dl = (p >> 17) & 127;
    int pos = atomicAdd(&cur[dl], 1);
    col[pos] = (int)(p & 0x1FFFFu);
  }
  if (b == 0 && tid == 0) ptr[N] = gbase[B1];
}

// ---------------- weight composition (fp32) ----------------
__global__ void k_compose_AB(const float* __restrict__ Wd, const float* __restrict__ Ws,
                             const float* __restrict__ Wu, float* __restrict__ AB){
  int idx = blockIdx.x*256 + threadIdx.x;      // 6*16384
  int mat = idx >> 14;
  int r   = (idx >> 7) & 127;
  int c   = idx & 127;
  int i   = mat >> 1;
  int isB = mat & 1;
  const float* P = (isB ? Ws : Wd) + i*16384 + r*128;
  const float* Q = Wu + i*32768 + (isB ? 16384 : 0) + c;
  float s = 0.f;
  for (int h = 0; h < 128; ++h) s += P[h] * Q[h*128];
  AB[idx] = s;
}

__global__ void k_compose_bias(const float* __restrict__ bd, const float* __restrict__ bs,
                               const float* __restrict__ bu, const float* __restrict__ Wu,
                               float* __restrict__ cv){
  int idx = blockIdx.x*256 + threadIdx.x;      // 3*128
  if (idx >= 384) return;
  int i = idx >> 7, h = idx & 127;
  float s = bu[i*128 + h];
  const float* Ut = Wu + i*32768 + h;
  const float* Ub = Ut + 16384;
  for (int k = 0; k < 128; ++k)
    s += bd[i*128 + k] * Ut[k*128] + bs[i*128 + k] * Ub[k*128];
  cv[idx] = s;
}

// pack B-fragment order, hi/lo interleaved per fragment
__global__ void k_pack_gene(const float* __restrict__ AB, const float* __restrict__ cv,
                            bf16* __restrict__ Wp, float* __restrict__ cg){
  int idx = blockIdx.x*256 + threadIdx.x;      // 8*12*512 = 49152
  int n0  = idx / 6144;
  int rem = idx - n0*6144;
  int ks  = rem >> 9;
  int lane = (rem >> 3) & 63;
  int j   = rem & 7;
  int k   = ks*32 + (lane >> 4)*8 + j;
  int col = n0*16 + (lane & 15);
  float v;
  if      (k < 128) v = 0.5f*(AB[0*16384 + k*128 + col] + AB[4*16384 + k*128 + col]);
  else if (k < 256) v = 0.5f* AB[1*16384 + (k-128)*128 + col];
  else              v = 0.5f* AB[5*16384 + (k-256)*128 + col];
  short h, l; split_bf(v, h, l);
  int f = idx >> 3;
  ((short*)Wp)[f*16 + j]     = h;
  ((short*)Wp)[f*16 + 8 + j] = l;
  if (idx < 128) cg[idx] = 0.5f*(cv[idx] + cv[256 + idx]);
}

__global__ void k_pack_dis(const float* __restrict__ AB, const float* __restrict__ cv,
                           bf16* __restrict__ Wp, float* __restrict__ cd){
  int idx = blockIdx.x*256 + threadIdx.x;      // 8*8*512 = 32768
  int n0  = idx >> 12;
  int ks  = (idx >> 9) & 7;
  int lane = (idx >> 3) & 63;
  int j   = idx & 7;
  int k   = ks*32 + (lane >> 4)*8 + j;
  int col = n0*16 + (lane & 15);
  float v = (k < 128) ? AB[2*16384 + k*128 + col] : AB[3*16384 + (k-128)*128 + col];
  short h, l; split_bf(v, h, l);
  int f = idx >> 3;
  ((short*)Wp)[f*16 + j]     = h;
  ((short*)Wp)[f*16 + 8 + j] = l;
  if (idx < 128) cd[idx] = cv[128 + idx];
}

// ---------------- fp32 -> bf16 table conversion ----------------
__global__ __launch_bounds__(256) void k_f2b(const float* __restrict__ X,
                                             unsigned short* __restrict__ Y, int n4){
  int idx = blockIdx.x*256 + threadIdx.x;
  if (idx >= n4) return;
  float4 v = ((const float4*)X)[idx];
  ushort4 o;
  o.x = f2b(v.x); o.y = f2b(v.y); o.z = f2b(v.z); o.w = f2b(v.w);
  ((ushort4*)Y)[idx] = o;
}

// ---------------- mean aggregation (quarter-wave per dst, bf16 in/out) ----------------
__global__ __launch_bounds__(256) void k_agg16(const bf16* __restrict__ Xb,
    const int* __restrict__ ptr, const int* __restrict__ col,
    bf16* __restrict__ Out, int N){
  int q = (blockIdx.x*256 + threadIdx.x) >> 4;
  int lane = threadIdx.x & 15;
  if (q >= N) return;
  int s = ptr[q], e = ptr[q+1];
  float a[8];
  #pragma unroll
  for (int j = 0; j < 8; ++j) a[j] = 0.f;
  for (int i = s; i < e; ++i){
    int src = col[i];
    bf16x8 v = *(const bf16x8*)(Xb + (size_t)src*DH + lane*8);
    #pragma unroll
    for (int j = 0; j < 8; ++j) a[j] += bf2f(v[j]);
  }
  float inv = 1.f / fmaxf((float)(e - s), 1.f);
  bf16x8 o;
  #pragma unroll
  for (int j = 0; j < 8; ++j) o[j] = (short)f2b(a[j]*inv);
  *(bf16x8*)(Out + (size_t)q*DH + lane*8) = o;
}

// ---------------- concat-K MFMA GEMM, LDS-staged B, bf16 out ----------------
// block = 256 thr / 4 waves / 64 rows; wave w owns n0 in {2w, 2w+1}, all 4 row-tiles.
// Per ks: stage 16 KB of B into LDS (double-buffered), 4 ds_read_b128/wave, 16 MFMA/wave.
__global__ __launch_bounds__(256) void k_gemm_cat(
    const bf16* __restrict__ X0, const bf16* __restrict__ X1, const bf16* __restrict__ X2,
    const bf16* __restrict__ Wp, const float* __restrict__ cvec,
    bf16* __restrict__ Out, int M, int KS){
  __shared__ short lds[2][8192];   // [buf]: hi at n0*512+lane*8, lo at 4096+...
  const int tid = threadIdx.x;
  const int wave = tid >> 6, lane = tid & 63;
  const int lrow = lane & 15, quad = lane >> 4;
  const int row0 = blockIdx.x*64;
  const bf16* Xs[3] = {X0, X1, X2};
  f32x4 acc[2][4];
  #pragma unroll
  for (int p = 0; p < 2; ++p)
    #pragma unroll
    for (int t = 0; t < 4; ++t) acc[p][t] = 0.0f;

  // staging: thread copies fragments fl0 = tid*2 and fl0+1 (same n0, adjacent lane_b)
  const int fl0  = tid*2;
  const int sn0  = fl0 >> 6;
  const int slb0 = fl0 & 63;

  bf16x8 cs[4];
  {
    const bf16x8* src = (const bf16x8*)(Wp + ((size_t)(sn0*KS + 0)*64 + slb0)*16);
    cs[0] = src[0]; cs[1] = src[1]; cs[2] = src[2]; cs[3] = src[3];
    short* hi = &lds[0][sn0*512 + slb0*8];
    short* lo = &lds[0][4096 + sn0*512 + slb0*8];
    *(bf16x8*)hi = cs[0]; *(bf16x8*)lo = cs[1];
    *(bf16x8*)(hi+8) = cs[2]; *(bf16x8*)(lo+8) = cs[3];
  }
  __syncthreads();

  int buf = 0;
  for (int ks = 0; ks < KS; ++ks){
    bf16x8 nxt[4];
    if (ks+1 < KS){
      const bf16x8* src = (const bf16x8*)(Wp + ((size_t)(sn0*KS + ks+1)*64 + slb0)*16);
      nxt[0] = src[0]; nxt[1] = src[1]; nxt[2] = src[2]; nxt[3] = src[3];
    }
    const bf16* Xm = Xs[ks >> 2];
    const int kk = (ks & 3)*32 + quad*8;
    bf16x8 a[4];
    #pragma unroll
    for (int t = 0; t < 4; ++t){
      int ar = row0 + t*16 + lrow; if (ar > M-1) ar = M-1;
      a[t] = *(const bf16x8*)(Xm + (size_t)ar*DH + kk);
    }
    const int n0a = wave*2, n0b = wave*2 + 1;
    bf16x8 bh0 = *(const bf16x8*)&lds[buf][n0a*512 + lane*8];
    bf16x8 bl0 = *(const bf16x8*)&lds[buf][4096 + n0a*512 + lane*8];
    bf16x8 bh1 = *(const bf16x8*)&lds[buf][n0b*512 + lane*8];
    bf16x8 bl1 = *(const bf16x8*)&lds[buf][4096 + n0b*512 + lane*8];
    #pragma unroll
    for (int t = 0; t < 4; ++t){
      acc[0][t] = __builtin_amdgcn_mfma_f32_16x16x32_bf16(a[t], bh0, acc[0][t], 0, 0, 0);
      acc[0][t] = __builtin_amdgcn_mfma_f32_16x16x32_bf16(a[t], bl0, acc[0][t], 0, 0, 0);
      acc[1][t] = __builtin_amdgcn_mfma_f32_16x16x32_bf16(a[t], bh1, acc[1][t], 0, 0, 0);
      acc[1][t] = __builtin_amdgcn_mfma_f32_16x16x32_bf16(a[t], bl1, acc[1][t], 0, 0, 0);
    }
    if (ks+1 < KS){
      int nb = buf ^ 1;
      short* hi = &lds[nb][sn0*512 + slb0*8];
      short* lo = &lds[nb][4096 + sn0*512 + slb0*8];
      *(bf16x8*)hi = nxt[0]; *(bf16x8*)lo = nxt[1];
      *(bf16x8*)(hi+8) = nxt[2]; *(bf16x8*)(lo+8) = nxt[3];
      __syncthreads();
      buf = nb;
    }
  }

  #pragma unroll
  for (int p = 0; p < 2; ++p){
    int n0 = wave*2 + p;
    int c = n0*16 + lrow;
    float cb = cvec[c];
    #pragma unroll
    for (int t = 0; t < 4; ++t){
      #pragma unroll
      for (int r = 0; r < 4; ++r){
        int row = row0 + t*16 + quad*4 + r;
        if (row < M) ((unsigned short*)Out)[(size_t)row*DH + c] = f2b(acc[p][t][r] + cb);
      }
    }
  }
}

// ---------------- BatchNorm stats from bf16 ----------------
__global__ __launch_bounds__(256) void k_bn_stats(const bf16* __restrict__ Xb, int N,
                                                  float* __restrict__ sums){
  __shared__ float acc[256];
  int tid = threadIdx.x;
  acc[tid] = 0.f;
  __syncthreads();
  int c8 = (tid & 15)*8;
  int rl = tid >> 4;
  float s[8], q[8];
  #pragma unroll
  for (int j = 0; j < 8; ++j){ s[j] = 0.f; q[j] = 0.f; }
  for (int r = blockIdx.x*16 + rl; r < N; r += gridDim.x*16){
    bf16x8 v = *(const bf16x8*)(Xb + (size_t)r*DH + c8);
    #pragma unroll
    for (int j = 0; j < 8; ++j){
      float f = bf2f(v[j]);
      s[j] += f; q[j] += f*f;
    }
  }
  #pragma unroll
  for (int j = 0; j < 8; ++j){
    atomicAdd(&acc[c8+j], s[j]);
    atomicAdd(&acc[128+c8+j], q[j]);
  }
  __syncthreads();
  atomicAdd(&sums[tid], acc[tid]);
}

// BN + LeakyReLU, bf16 in/out
__global__ __launch_bounds__(256) void k_bn_apply(const bf16* __restrict__ Xb,
    const float* __restrict__ sums, const float* __restrict__ gamma, const float* __restrict__ beta,
    unsigned short* __restrict__ Yb, int total8, float invN){
  __shared__ float sc[128], sb[128];
  int tid = threadIdx.x;
  if (tid < 128){
    float m = sums[tid]*invN;
    float v = sums[128 + tid]*invN - m*m;
    float s = rsqrtf(v + 1e-5f) * gamma[tid];
    sc[tid] = s;
    sb[tid] = beta[tid] - m*s;
  }
  __syncthreads();
  for (int idx = blockIdx.x*blockDim.x + tid; idx < total8; idx += gridDim.x*blockDim.x){
    bf16x8 v = ((const bf16x8*)Xb)[idx];
    int c = (idx & 15)*8;
    bf16x8 o;
    #pragma unroll
    for (int j = 0; j < 8; ++j){
      float y = bf2f(v[j])*sc[c+j] + sb[c+j];
      y = y >= 0.f ? y : 0.01f*y;
      o[j] = (short)f2b(y);
    }
    ((bf16x8*)Yb)[idx] = o;
  }
}

// ---------------- decoder (16 lanes per label edge, bf16 in) ----------------
__global__ __launch_bounds__(256) void k_decode(const bf16* __restrict__ G, const bf16* __restrict__ Dd,
    const int* __restrict__ ls, const int* __restrict__ ld, float* __restrict__ out, int E){
  int q = (blockIdx.x*256 + threadIdx.x) >> 4;
  int lane = threadIdx.x & 15;
  if (q >= E) return;
  int a = ls[q], b = ld[q];
  bf16x8 g = *(const bf16x8*)(G  + (size_t)a*DH + lane*8);
  bf16x8 d = *(const bf16x8*)(Dd + (size_t)b*DH + lane*8);
  float s = 0.f;
  #pragma unroll
  for (int j = 0; j < 8; ++j) s += bf2f(g[j])*bf2f(d[j]);
  #pragma unroll
  for (int off = 8; off; off >>= 1) s += __shfl_down(s, off, 16);
  if (lane == 0) out[q] = s;
}

// ---------------- launch ----------------
extern "C" void kernel_launch(void* const* d_in, const int* in_sizes, int n_in,
                              void* d_out, int out_size, void* d_ws, size_t ws_size,
                              hipStream_t stream){
  const float* x_gene = (const float*)d_in[0];
  const float* x_dis  = (const float*)d_in[1];
  const float* Wd1 = (const float*)d_in[2];
  const float* Ws1 = (const float*)d_in[3];
  const float* Wu1 = (const float*)d_in[4];
  const float* bd1 = (const float*)d_in[5];
  const float* bs1 = (const float*)d_in[6];
  const float* bu1 = (const float*)d_in[7];
  const float* Wd2 = (const float*)d_in[8];
  const float* Ws2 = (const float*)d_in[9];
  const float* Wu2 = (const float*)d_in[10];
  const float* bd2 = (const float*)d_in[11];
  const float* bs2 = (const float*)d_in[12];
  const float* bu2 = (const float*)d_in[13];
  const float* bng = (const float*)d_in[14];
  const float* bnb = (const float*)d_in[15];
  const int* gg_src  = (const int*)d_in[16];
  const int* gg_dst  = (const int*)d_in[17];
  const int* gda_src = (const int*)d_in[18];
  const int* gda_dst = (const int*)d_in[19];
  const int* lsrc = (const int*)d_in[20];
  const int* ldst = (const int*)d_in[21];

  char* ws = (char*)d_ws;
  size_t off = 0;
  auto alloc = [&](size_t bytes)->void*{
    void* p = ws + off; off += (bytes + 255) & ~(size_t)255; return p;
  };
  int* gg_ptr  = (int*)alloc((NG+2)*4);
  int* gg_col  = (int*)alloc((size_t)EGG*4);
  int* gda_ptr = (int*)alloc((ND+2)*4);
  int* gda_col = (int*)alloc((size_t)EGDA*4);
  int* rev_ptr = (int*)alloc((NG+2)*4);
  int* rev_col = (int*)alloc((size_t)EGDA*4);
  int* hist    = (int*)alloc(400*4);
  int* gbase   = (int*)alloc(400*4);
  int* gcur    = (int*)alloc(400*4);
  unsigned* pk = (unsigned*)alloc((size_t)EGG*4);
  float* AB1 = (float*)alloc(6*16384*4);
  float* AB2 = (float*)alloc(6*16384*4);
  float* cv1 = (float*)alloc(3*128*4);
  float* cv2 = (float*)alloc(3*128*4);
  float* cg1 = (float*)alloc(128*4);
  float* cd1 = (float*)alloc(128*4);
  float* cg2 = (float*)alloc(128*4);
  float* cd2 = (float*)alloc(128*4);
  bf16* Wg1  = (bf16*)alloc(98304*2);
  bf16* Wp1  = (bf16*)alloc(65536*2);
  bf16* Wg2  = (bf16*)alloc(98304*2);
  bf16* Wp2  = (bf16*)alloc(65536*2);
  bf16* xgb  = (bf16*)alloc((size_t)NG*DH*2);
  bf16* xdb  = (bf16*)alloc((size_t)ND*DH*2);
  bf16* aggGGb  = (bf16*)alloc((size_t)NG*DH*2);
  bf16* aggREVb = (bf16*)alloc((size_t)NG*DH*2);
  bf16* aggGDAb = (bf16*)alloc((size_t)ND*DH*2);
  bf16* Xg2b = (bf16*)alloc((size_t)NG*DH*2);
  bf16* Xd2b = (bf16*)alloc((size_t)ND*DH*2);
  bf16* outgb = (bf16*)alloc((size_t)NG*DH*2);
  bf16* outdb = (bf16*)alloc((size_t)ND*DH*2);
  float* bnsum = (float*)alloc(2*256*4);

  const int B1G = 391, B1Gp = 392;
  const int B1D = 157, B1Dp = 160;

  // --- CSR: gene->gene grouped by gg_dst ---
  hipMemsetAsync(hist, 0, B1Gp*4, stream);
  k_hist1<<<256,256,0,stream>>>(gg_dst, EGG, hist, B1G);
  k_exscan<<<1,1024,0,stream>>>(hist, gbase, gcur, B1Gp);
  k_scatter1<<<(EGG+4095)/4096,256,0,stream>>>(gg_dst, gg_src, EGG, gcur, pk, B1G);
  k_csr2<<<B1G,256,0,stream>>>(pk, gbase, gg_ptr, gg_col, NG, B1G);
  // --- CSR: gene->disease grouped by gda_dst ---
  hipMemsetAsync(hist, 0, B1Dp*4, stream);
  k_hist1<<<256,256,0,stream>>>(gda_dst, EGDA, hist, B1D);
  k_exscan<<<1,1024,0,stream>>>(hist, gbase, gcur, B1Dp);
  k_scatter1<<<(EGDA+4095)/4096,256,0,stream>>>(gda_dst, gda_src, EGDA, gcur, pk, B1D);
  k_csr2<<<B1D,256,0,stream>>>(pk, gbase, gda_ptr, gda_col, ND, B1D);
  // --- CSR: disease->gene (reverse) grouped by gda_src ---
  hipMemsetAsync(hist, 0, B1Gp*4, stream);
  k_hist1<<<256,256,0,stream>>>(gda_src, EGDA, hist, B1G);
  k_exscan<<<1,1024,0,stream>>>(hist, gbase, gcur, B1Gp);
  k_scatter1<<<(EGDA+4095)/4096,256,0,stream>>>(gda_src, gda_dst, EGDA, gcur, pk, B1G);
  k_csr2<<<B1G,256,0,stream>>>(pk, gbase, rev_ptr, rev_col, NG, B1G);

  // --- composed weights (both layers) ---
  k_compose_AB<<<384,256,0,stream>>>(Wd1, Ws1, Wu1, AB1);
  k_compose_AB<<<384,256,0,stream>>>(Wd2, Ws2, Wu2, AB2);
  k_compose_bias<<<2,256,0,stream>>>(bd1, bs1, bu1, Wu1, cv1);
  k_compose_bias<<<2,256,0,stream>>>(bd2, bs2, bu2, Wu2, cv2);
  k_pack_gene<<<192,256,0,stream>>>(AB1, cv1, Wg1, cg1);
  k_pack_gene<<<192,256,0,stream>>>(AB2, cv2, Wg2, cg2);
  k_pack_dis<<<128,256,0,stream>>>(AB1, cv1, Wp1, cd1);
  k_pack_dis<<<128,256,0,stream>>>(AB2, cv2, Wp2, cd2);

  // --- bf16 feature tables ---
  k_f2b<<<(NG*DH/4+255)/256,256,0,stream>>>(x_gene, (unsigned short*)xgb, NG*DH/4);
  k_f2b<<<(ND*DH/4+255)/256,256,0,stream>>>(x_dis,  (unsigned short*)xdb, ND*DH/4);

  // --- layer 1 ---
  k_agg16<<<(NG*16+255)/256,256,0,stream>>>(xgb, gg_ptr, gg_col, aggGGb, NG);
  k_agg16<<<(ND*16+255)/256,256,0,stream>>>(xgb, gda_ptr, gda_col, aggGDAb, ND);
  k_agg16<<<(NG*16+255)/256,256,0,stream>>>(xdb, rev_ptr, rev_col, aggREVb, NG);
  k_gemm_cat<<<(NG+63)/64,256,0,stream>>>(xgb, aggGGb, aggREVb, Wg1, cg1, outgb, NG, 12);
  k_gemm_cat<<<(ND+63)/64,256,0,stream>>>(xdb, aggGDAb, aggGDAb, Wp1, cd1, outdb, ND, 8);
  hipMemsetAsync(bnsum, 0, 2*256*4, stream);
  k_bn_stats<<<256,256,0,stream>>>(outgb, NG, bnsum);
  k_bn_stats<<<256,256,0,stream>>>(outdb, ND, bnsum + 256);
  k_bn_apply<<<512,256,0,stream>>>(outgb, bnsum, bng, bnb, (unsigned short*)Xg2b, NG*DH/8, 1.f/NG);
  k_bn_apply<<<512,256,0,stream>>>(outdb, bnsum + 256, bng + 128, bnb + 128, (unsigned short*)Xd2b, ND*DH/8, 1.f/ND);

  // --- layer 2 ---
  k_agg16<<<(NG*16+255)/256,256,0,stream>>>(Xg2b, gg_ptr, gg_col, aggGGb, NG);
  k_agg16<<<(ND*16+255)/256,256,0,stream>>>(Xg2b, gda_ptr, gda_col, aggGDAb, ND);
  k_agg16<<<(NG*16+255)/256,256,0,stream>>>(Xd2b, rev_ptr, rev_col, aggREVb, NG);
  k_gemm_cat<<<(NG+63)/64,256,0,stream>>>(Xg2b, aggGGb, aggREVb, Wg2, cg2, outgb, NG, 12);
  k_gemm_cat<<<(ND+63)/64,256,0,stream>>>(Xd2b, aggGDAb, aggGDAb, Wp2, cd2, outdb, ND, 8);

  // --- decoder ---
  k_decode<<<(ELAB*16+255)/256,256,0,stream>>>(outgb, outdb, lsrc, ldst, (float*)d_out, ELAB);
}

// Round 6
// 414.650 us; speedup vs baseline: 2.8445x; 1.4015x over previous
//
#include <hip/hip_runtime.h>
#include <hip/hip_bf16.h>
#include <cstddef>

#define NG   50000
#define ND   20000
#define DH   128
#define EGG  800000
#define EGDA 400000
#define ELAB 200000

// bucket layout: graph0 (gg by dst) 391, graph1 (gda by dst) 157, graph2 (gda by src) 391
#define B1G 391
#define B1D 157
#define TB  939            // total buckets
#define TBP 940            // padded (multiple of 4)
#define PB0 0
#define PB1 (NG+1)
#define PB2 (NG+1+ND+1)

typedef __hip_bfloat16  bf16;
typedef __attribute__((ext_vector_type(8))) short bf16x8;
typedef __attribute__((ext_vector_type(4))) float f32x4;

__device__ __forceinline__ float bf2f(short s){
  return __uint_as_float(((unsigned)(unsigned short)s) << 16);
}
__device__ __forceinline__ unsigned short f2b(float x){
  unsigned u = __float_as_uint(x);
  return (unsigned short)((u + 0x7FFF + ((u >> 16) & 1)) >> 16);
}

// ---------------- CSR build (all 3 graphs in one pass-set) ----------------
__global__ __launch_bounds__(256) void k_hist1(const int* __restrict__ k0, const int* __restrict__ k1,
                                               const int* __restrict__ k2, int* __restrict__ hist){
  __shared__ int lh[400];
  const int g = blockIdx.y;
  const int n  = (g == 0) ? EGG : EGDA;
  const int B1 = (g == 1) ? B1D : B1G;
  const int bb = (g == 0) ? 0 : (g == 1 ? B1G : B1G + B1D);
  const int* key = (g == 0) ? k0 : (g == 1 ? k1 : k2);
  for (int t = threadIdx.x; t < B1; t += 256) lh[t] = 0;
  __syncthreads();
  for (int i = blockIdx.x*blockDim.x + threadIdx.x; i < n; i += gridDim.x*blockDim.x)
    atomicAdd(&lh[key[i] >> 7], 1);
  __syncthreads();
  for (int t = threadIdx.x; t < B1; t += 256){
    int c = lh[t];
    if (c) atomicAdd(&hist[bb + t], c);
  }
}

__global__ __launch_bounds__(1024) void k_exscan(const int* __restrict__ cnt,
                                                 int* __restrict__ ptr, int* __restrict__ cur, int n){
  __shared__ int wsum[16];
  __shared__ int carry;
  const int tid = threadIdx.x, lane = tid & 63, wid = tid >> 6;
  if (tid == 0) carry = 0;
  __syncthreads();
  for (int base = 0; base < n; base += 4096){
    int i0 = base + tid*4;
    int4 v = {0,0,0,0};
    if (i0 < n) v = *(const int4*)(cnt + i0);
    int tsum = v.x + v.y + v.z + v.w;
    int x = tsum;
    #pragma unroll
    for (int off = 1; off < 64; off <<= 1){
      int t = __shfl_up(x, off);
      if (lane >= off) x += t;
    }
    if (lane == 63) wsum[wid] = x;
    __syncthreads();
    if (wid == 0 && lane < 16){
      int w = wsum[lane];
      #pragma unroll
      for (int off = 1; off < 16; off <<= 1){
        int t = __shfl_up(w, off);
        if (lane >= off) w += t;
      }
      wsum[lane] = w;
    }
    __syncthreads();
    int waveoff = wid ? wsum[wid-1] : 0;
    if (i0 < n){
      int ex = carry + waveoff + x - tsum;
      int4 o;
      o.x = ex; o.y = ex + v.x; o.z = o.y + v.y; o.w = o.z + v.z;
      *(int4*)(ptr + i0) = o;
      *(int4*)(cur + i0) = o;
    }
    int total = wsum[15];
    __syncthreads();
    if (tid == 0) carry += total;
    __syncthreads();
  }
  if (tid == 0) ptr[n] = carry;
}

__global__ __launch_bounds__(256) void k_scatter1(const int* __restrict__ k0, const int* __restrict__ v0,
                                                  const int* __restrict__ k1, const int* __restrict__ v1,
                                                  int* __restrict__ gcur, unsigned* __restrict__ pk){
  __shared__ int lh[400];
  __shared__ int base[400];
  const int g = blockIdx.y;
  const int n  = (g == 0) ? EGG : EGDA;
  const int B1 = (g == 1) ? B1D : B1G;
  const int bb = (g == 0) ? 0 : (g == 1 ? B1G : B1G + B1D);
  const int* key = (g == 0) ? k0 : (g == 1 ? k1 : v1);
  const int* val = (g == 0) ? v0 : (g == 1 ? v1 : k1);
  const int tid = threadIdx.x;
  const int chunk0 = blockIdx.x*4096;
  if (chunk0 >= n) return;
  for (int t = tid; t < B1; t += 256) lh[t] = 0;
  __syncthreads();
  int kd[16], vv[16];
  #pragma unroll
  for (int it = 0; it < 16; ++it){
    int i = chunk0 + it*256 + tid;
    int k = -1, v = 0;
    if (i < n){ k = key[i]; v = val[i]; atomicAdd(&lh[k >> 7], 1); }
    kd[it] = k; vv[it] = v;
  }
  __syncthreads();
  for (int t = tid; t < B1; t += 256){
    int c = lh[t];
    base[t] = c ? atomicAdd(&gcur[bb + t], c) : 0;
    lh[t] = 0;
  }
  __syncthreads();
  #pragma unroll
  for (int it = 0; it < 16; ++it){
    int k = kd[it];
    if (k >= 0){
      int b = k >> 7;
      int p = base[b] + atomicAdd(&lh[b], 1);
      pk[p] = ((unsigned)(k & 127) << 17) | (unsigned)vv[it];
    }
  }
}

__global__ __launch_bounds__(256) void k_csr2(const unsigned* __restrict__ pk,
                                              const int* __restrict__ gbase,
                                              int* __restrict__ ptr_all, int* __restrict__ col){
  __shared__ int lh[128];
  __shared__ int cur[128];
  __shared__ int sh0;
  const int b = blockIdx.x, tid = threadIdx.x;
  int g, lb, pbase, Ngr, bend;
  if (b < B1G)            { g = 0; lb = b;            pbase = PB0; Ngr = NG; bend = B1G; }
  else if (b < B1G + B1D) { g = 1; lb = b - B1G;      pbase = PB1; Ngr = ND; bend = B1G + B1D; }
  else                    { g = 2; lb = b - B1G - B1D; pbase = PB2; Ngr = NG; bend = TB; }
  const int s = gbase[b], e = gbase[b+1];
  if (tid < 128) lh[tid] = 0;
  __syncthreads();
  for (int i = s + tid; i < e; i += 256)
    atomicAdd(&lh[(pk[i] >> 17) & 127], 1);
  __syncthreads();
  int lane = tid & 63;
  int v = 0, x = 0;
  if (tid < 128){
    v = lh[tid]; x = v;
    #pragma unroll
    for (int o = 1; o < 64; o <<= 1){
      int t = __shfl_up(x, o);
      if (lane >= o) x += t;
    }
    if (tid == 63) sh0 = x;
  }
  __syncthreads();
  if (tid < 128){
    int excl = x - v + (tid >= 64 ? sh0 : 0);
    cur[tid] = s + excl;
    int loc = (lb << 7) + tid;
    if (loc < Ngr) ptr_all[pbase + loc] = s + excl;
  }
  __syncthreads();
  for (int i = s + tid; i < e; i += 256){
    unsigned p = pk[i];
    int dl = (p >> 17) & 127;
    int pos = atomicAdd(&cur[dl], 1);
    col[pos] = (int)(p & 0x1FFFFu);
  }
  if (lb == 0 && tid == 0) ptr_all[pbase + Ngr] = gbase[bend];
}

// ---------------- weight composition (both layers fused) ----------------
__global__ __launch_bounds__(256) void k_compose_AB(
    const float* __restrict__ Wd1, const float* __restrict__ Ws1, const float* __restrict__ Wu1,
    const float* __restrict__ Wd2, const float* __restrict__ Ws2, const float* __restrict__ Wu2,
    float* __restrict__ AB){
  int idx = blockIdx.x*256 + threadIdx.x;       // 2*6*16384
  int layer = idx / 98304;
  int r0 = idx - layer*98304;
  int mat = r0 >> 14;
  int r   = (r0 >> 7) & 127;
  int c   = r0 & 127;
  int i   = mat >> 1;
  int isB = mat & 1;
  const float* Wd = layer ? Wd2 : Wd1;
  const float* Ws = layer ? Ws2 : Ws1;
  const float* Wu = layer ? Wu2 : Wu1;
  const float* P = (isB ? Ws : Wd) + i*16384 + r*128;
  const float* Q = Wu + i*32768 + (isB ? 16384 : 0) + c;
  float s = 0.f;
  for (int h = 0; h < 128; ++h) s += P[h] * Q[h*128];
  AB[idx] = s;
}

__global__ __launch_bounds__(256) void k_compose_bias(
    const float* __restrict__ bd1, const float* __restrict__ bs1, const float* __restrict__ bu1, const float* __restrict__ Wu1,
    const float* __restrict__ bd2, const float* __restrict__ bs2, const float* __restrict__ bu2, const float* __restrict__ Wu2,
    float* __restrict__ cv){
  int idx = blockIdx.x*256 + threadIdx.x;       // 2*384
  if (idx >= 768) return;
  int layer = idx / 384;
  int r = idx - layer*384;
  int i = r >> 7, h = r & 127;
  const float* bd = layer ? bd2 : bd1;
  const float* bs = layer ? bs2 : bs1;
  const float* bu = layer ? bu2 : bu1;
  const float* Wu = layer ? Wu2 : Wu1;
  float s = bu[i*128 + h];
  const float* Ut = Wu + i*32768 + h;
  const float* Ub = Ut + 16384;
  for (int k = 0; k < 128; ++k)
    s += bd[i*128 + k] * Ut[k*128] + bs[i*128 + k] * Ub[k*128];
  cv[idx] = s;
}

// pack B-fragment order (hi-only), both layers + gene/dis in one kernel
// gene: W[f*8+j], f=(n0*12+ks)*64+lane, elem W[k][col], k=ks*32+(lane>>4)*8+j, col=n0*16+(lane&15)
__global__ __launch_bounds__(256) void k_pack(const float* __restrict__ AB, const float* __restrict__ cv,
                                              bf16* __restrict__ Wg1, bf16* __restrict__ Wd1p,
                                              bf16* __restrict__ Wg2, bf16* __restrict__ Wd2p,
                                              float* __restrict__ cg1, float* __restrict__ cd1,
                                              float* __restrict__ cg2, float* __restrict__ cd2){
  int idx = blockIdx.x*256 + threadIdx.x;       // 2*(49152+32768) = 163840
  int layer = idx / 81920;
  int rem = idx - layer*81920;
  const float* ABl = AB + layer*98304;
  const float* cvl = cv + layer*384;
  if (rem < 49152){
    int n0  = rem / 6144;
    int r2  = rem - n0*6144;
    int ks  = r2 >> 9;
    int lane = (r2 >> 3) & 63;
    int j   = r2 & 7;
    int k   = ks*32 + (lane >> 4)*8 + j;
    int c   = n0*16 + (lane & 15);
    float v;
    if      (k < 128) v = 0.5f*(ABl[0*16384 + k*128 + c] + ABl[4*16384 + k*128 + c]);
    else if (k < 256) v = 0.5f* ABl[1*16384 + (k-128)*128 + c];
    else              v = 0.5f* ABl[5*16384 + (k-256)*128 + c];
    bf16* W = layer ? Wg2 : Wg1;
    ((unsigned short*)W)[rem] = f2b(v);
    if (rem < 128){
      float* cg = layer ? cg2 : cg1;
      cg[rem] = 0.5f*(cvl[rem] + cvl[256 + rem]);
    }
  } else {
    int d = rem - 49152;
    int n0  = d >> 12;
    int ks  = (d >> 9) & 7;
    int lane = (d >> 3) & 63;
    int j   = d & 7;
    int k   = ks*32 + (lane >> 4)*8 + j;
    int c   = n0*16 + (lane & 15);
    float v = (k < 128) ? ABl[2*16384 + k*128 + c] : ABl[3*16384 + (k-128)*128 + c];
    bf16* W = layer ? Wd2p : Wd1p;
    ((unsigned short*)W)[d] = f2b(v);
    if (d < 128){
      float* cd = layer ? cd2 : cd1;
      cd[d] = cvl[128 + d];
    }
  }
}

// ---------------- fp32 -> bf16 tables (both) ----------------
__global__ __launch_bounds__(256) void k_f2b(const float* __restrict__ Xg, const float* __restrict__ Xd,
                                             unsigned short* __restrict__ Yg, unsigned short* __restrict__ Yd){
  int idx = blockIdx.x*256 + threadIdx.x;       // (NG+ND)*32
  const int GQ = NG*32;
  if (idx >= GQ + ND*32) return;
  const float* X; unsigned short* Y; int i;
  if (idx < GQ){ X = Xg; Y = Yg; i = idx; }
  else         { X = Xd; Y = Yd; i = idx - GQ; }
  float4 v = ((const float4*)X)[i];
  ushort4 o;
  o.x = f2b(v.x); o.y = f2b(v.y); o.z = f2b(v.z); o.w = f2b(v.w);
  ((ushort4*)Y)[i] = o;
}

// ---------------- mean aggregation: 3 graphs, one kernel ----------------
__global__ __launch_bounds__(256) void k_agg(const bf16* __restrict__ Xg, const bf16* __restrict__ Xd,
    const int* __restrict__ ptr_all, const int* __restrict__ col,
    bf16* __restrict__ OutGG, bf16* __restrict__ OutGDA, bf16* __restrict__ OutREV){
  int q = (blockIdx.x*256 + threadIdx.x) >> 4;
  int lane = threadIdx.x & 15;
  const bf16* X; bf16* Out; const int* ptr; int dst;
  if (q < NG)          { X = Xg; Out = OutGG;  ptr = ptr_all + PB0; dst = q; }
  else if (q < NG+ND)  { X = Xg; Out = OutGDA; ptr = ptr_all + PB1; dst = q - NG; }
  else                 { X = Xd; Out = OutREV; ptr = ptr_all + PB2; dst = q - NG - ND; }
  int s = ptr[dst], e = ptr[dst+1];
  float a[8];
  #pragma unroll
  for (int j = 0; j < 8; ++j) a[j] = 0.f;
  for (int i = s; i < e; ++i){
    int src = col[i];
    bf16x8 v = *(const bf16x8*)(X + (size_t)src*DH + lane*8);
    #pragma unroll
    for (int j = 0; j < 8; ++j) a[j] += bf2f(v[j]);
  }
  float inv = 1.f / fmaxf((float)(e - s), 1.f);
  bf16x8 o;
  #pragma unroll
  for (int j = 0; j < 8; ++j) o[j] = (short)f2b(a[j]*inv);
  *(bf16x8*)(Out + (size_t)dst*DH + lane*8) = o;
}

// ---------------- concat-K MFMA GEMM: no LDS, B from global (L2), hi-only ----------------
template<int KS>
__device__ __forceinline__ void gemm_body(
    const bf16* __restrict__ X0, const bf16* __restrict__ X1, const bf16* __restrict__ X2,
    const bf16* __restrict__ Wp, const float* __restrict__ cvec,
    unsigned short* __restrict__ Out, int M, int blk){
  const int tid = threadIdx.x;
  const int wave = tid >> 6, lane = tid & 63;
  const int lrow = lane & 15, quad = lane >> 4;
  const int row0 = blk*64;
  const bf16* Xs[3] = {X0, X1, X2};
  f32x4 acc[2][4];
  #pragma unroll
  for (int p = 0; p < 2; ++p)
    #pragma unroll
    for (int t = 0; t < 4; ++t) acc[p][t] = 0.0f;
  const bf16x8* wp = (const bf16x8*)Wp;
  const int f00 = (2*wave*KS)*64 + lane;
  #pragma unroll
  for (int ks = 0; ks < KS; ++ks){
    const bf16* Xm = Xs[ks >> 2];
    const int kk = (ks & 3)*32 + quad*8;
    bf16x8 a[4];
    #pragma unroll
    for (int t = 0; t < 4; ++t){
      int ar = row0 + t*16 + lrow; if (ar > M-1) ar = M-1;
      a[t] = *(const bf16x8*)(Xm + (size_t)ar*DH + kk);
    }
    bf16x8 b0 = wp[f00 + ks*64];
    bf16x8 b1 = wp[f00 + (KS + ks)*64];
    #pragma unroll
    for (int t = 0; t < 4; ++t){
      acc[0][t] = __builtin_amdgcn_mfma_f32_16x16x32_bf16(a[t], b0, acc[0][t], 0, 0, 0);
      acc[1][t] = __builtin_amdgcn_mfma_f32_16x16x32_bf16(a[t], b1, acc[1][t], 0, 0, 0);
    }
  }
  #pragma unroll
  for (int p = 0; p < 2; ++p){
    int c = (2*wave + p)*16 + lrow;
    float cb = cvec[c];
    #pragma unroll
    for (int t = 0; t < 4; ++t){
      #pragma unroll
      for (int r = 0; r < 4; ++r){
        int row = row0 + t*16 + quad*4 + r;
        if (row < M) Out[(size_t)row*DH + c] = f2b(acc[p][t][r] + cb);
      }
    }
  }
}

#define GBGENE ((NG+63)/64)
#define GBDIS  ((ND+63)/64)

__global__ __launch_bounds__(256) void k_gemm(
    const bf16* __restrict__ Xg, const bf16* __restrict__ Ag, const bf16* __restrict__ Rg,
    const bf16* __restrict__ Wg, const float* __restrict__ cg, unsigned short* __restrict__ Og,
    const bf16* __restrict__ Xd, const bf16* __restrict__ Ad,
    const bf16* __restrict__ Wd, const float* __restrict__ cd, unsigned short* __restrict__ Od){
  if ((int)blockIdx.x < GBGENE)
    gemm_body<12>(Xg, Ag, Rg, Wg, cg, Og, NG, blockIdx.x);
  else
    gemm_body<8>(Xd, Ad, Ad, Wd, cd, Od, ND, blockIdx.x - GBGENE);
}

// ---------------- BatchNorm stats (both matrices, one kernel) ----------------
#define SBG 192
#define SBD 64
__global__ __launch_bounds__(256) void k_bn_stats(const bf16* __restrict__ Xgb, const bf16* __restrict__ Xdb,
                                                  float* __restrict__ sums){
  __shared__ float acc[256];
  int tid = threadIdx.x;
  acc[tid] = 0.f;
  __syncthreads();
  int g = (int)blockIdx.x >= SBG;
  int bidx = blockIdx.x - (g ? SBG : 0);
  int NB = g ? SBD : SBG;
  int N  = g ? ND : NG;
  const bf16* Xb = g ? Xdb : Xgb;
  float* sm = sums + g*256;
  int c8 = (tid & 15)*8;
  int rl = tid >> 4;
  float s[8], q[8];
  #pragma unroll
  for (int j = 0; j < 8; ++j){ s[j] = 0.f; q[j] = 0.f; }
  for (int r = bidx*16 + rl; r < N; r += NB*16){
    bf16x8 v = *(const bf16x8*)(Xb + (size_t)r*DH + c8);
    #pragma unroll
    for (int j = 0; j < 8; ++j){
      float f = bf2f(v[j]);
      s[j] += f; q[j] += f*f;
    }
  }
  #pragma unroll
  for (int j = 0; j < 8; ++j){
    atomicAdd(&acc[c8+j], s[j]);
    atomicAdd(&acc[128+c8+j], q[j]);
  }
  __syncthreads();
  atomicAdd(&sm[tid], acc[tid]);
}

// BN + LeakyReLU, both matrices
__global__ __launch_bounds__(256) void k_bn_apply(const bf16* __restrict__ Xgb, const bf16* __restrict__ Xdb,
    const float* __restrict__ sums, const float* __restrict__ gamma, const float* __restrict__ beta,
    unsigned short* __restrict__ Yg, unsigned short* __restrict__ Yd){
  __shared__ float sc[256], sb[256];
  int tid = threadIdx.x;
  {
    int g = tid >> 7, c = tid & 127;
    float invN = g ? (1.f/ND) : (1.f/NG);
    const float* sm = sums + g*256;
    float m = sm[c]*invN;
    float v = sm[128 + c]*invN - m*m;
    float s = rsqrtf(v + 1e-5f) * gamma[g*128 + c];
    sc[tid] = s;
    sb[tid] = beta[g*128 + c] - m*s;
  }
  __syncthreads();
  const int GT = NG*16;
  const int TOT = GT + ND*16;
  for (int idx = blockIdx.x*256 + tid; idx < TOT; idx += gridDim.x*256){
    const bf16x8* src; bf16x8* dst; int i, cb;
    if (idx < GT){ src = (const bf16x8*)Xgb; dst = (bf16x8*)Yg; i = idx; cb = 0; }
    else         { src = (const bf16x8*)Xdb; dst = (bf16x8*)Yd; i = idx - GT; cb = 128; }
    bf16x8 v = src[i];
    int c = cb + (i & 15)*8;
    bf16x8 o;
    #pragma unroll
    for (int j = 0; j < 8; ++j){
      float y = bf2f(v[j])*sc[c+j] + sb[c+j];
      y = y >= 0.f ? y : 0.01f*y;
      o[j] = (short)f2b(y);
    }
    dst[i] = o;
  }
}

// ---------------- decoder ----------------
__global__ __launch_bounds__(256) void k_decode(const bf16* __restrict__ G, const bf16* __restrict__ Dd,
    const int* __restrict__ ls, const int* __restrict__ ld, float* __restrict__ out, int E){
  int q = (blockIdx.x*256 + threadIdx.x) >> 4;
  int lane = threadIdx.x & 15;
  if (q >= E) return;
  int a = ls[q], b = ld[q];
  bf16x8 g = *(const bf16x8*)(G  + (size_t)a*DH + lane*8);
  bf16x8 d = *(const bf16x8*)(Dd + (size_t)b*DH + lane*8);
  float s = 0.f;
  #pragma unroll
  for (int j = 0; j < 8; ++j) s += bf2f(g[j])*bf2f(d[j]);
  #pragma unroll
  for (int off = 8; off; off >>= 1) s += __shfl_down(s, off, 16);
  if (lane == 0) out[q] = s;
}

// ---------------- launch ----------------
extern "C" void kernel_launch(void* const* d_in, const int* in_sizes, int n_in,
                              void* d_out, int out_size, void* d_ws, size_t ws_size,
                              hipStream_t stream){
  const float* x_gene = (const float*)d_in[0];
  const float* x_dis  = (const float*)d_in[1];
  const float* Wd1 = (const float*)d_in[2];
  const float* Ws1 = (const float*)d_in[3];
  const float* Wu1 = (const float*)d_in[4];
  const float* bd1 = (const float*)d_in[5];
  const float* bs1 = (const float*)d_in[6];
  const float* bu1 = (const float*)d_in[7];
  const float* Wd2 = (const float*)d_in[8];
  const float* Ws2 = (const float*)d_in[9];
  const float* Wu2 = (const float*)d_in[10];
  const float* bd2 = (const float*)d_in[11];
  const float* bs2 = (const float*)d_in[12];
  const float* bu2 = (const float*)d_in[13];
  const float* bng = (const float*)d_in[14];
  const float* bnb = (const float*)d_in[15];
  const int* gg_src  = (const int*)d_in[16];
  const int* gg_dst  = (const int*)d_in[17];
  const int* gda_src = (const int*)d_in[18];
  const int* gda_dst = (const int*)d_in[19];
  const int* lsrc = (const int*)d_in[20];
  const int* ldst = (const int*)d_in[21];

  char* ws = (char*)d_ws;
  size_t off = 0;
  auto alloc = [&](size_t bytes)->void*{
    void* p = ws + off; off += (bytes + 255) & ~(size_t)255; return p;
  };
  int* hist    = (int*)alloc(960*4);         // memset with bnsum (contiguous)
  float* bnsum = (float*)alloc(2*256*4);
  int* gbase   = (int*)alloc(960*4);
  int* gcur    = (int*)alloc(960*4);
  int* ptr_all = (int*)alloc((size_t)(NG+1+ND+1+NG+1)*4);
  int* col     = (int*)alloc((size_t)(EGG+2*EGDA)*4);
  unsigned* pk = (unsigned*)alloc((size_t)(EGG+2*EGDA)*4);
  float* AB  = (float*)alloc(2*98304*4);
  float* cv  = (float*)alloc(2*384*4);
  float* cg1 = (float*)alloc(128*4);
  float* cd1 = (float*)alloc(128*4);
  float* cg2 = (float*)alloc(128*4);
  float* cd2 = (float*)alloc(128*4);
  bf16* Wg1  = (bf16*)alloc(49152*2);
  bf16* Wp1  = (bf16*)alloc(32768*2);
  bf16* Wg2  = (bf16*)alloc(49152*2);
  bf16* Wp2  = (bf16*)alloc(32768*2);
  bf16* xgb  = (bf16*)alloc((size_t)NG*DH*2);
  bf16* xdb  = (bf16*)alloc((size_t)ND*DH*2);
  bf16* aggGGb  = (bf16*)alloc((size_t)NG*DH*2);
  bf16* aggREVb = (bf16*)alloc((size_t)NG*DH*2);
  bf16* aggGDAb = (bf16*)alloc((size_t)ND*DH*2);
  bf16* Xg2b = (bf16*)alloc((size_t)NG*DH*2);
  bf16* Xd2b = (bf16*)alloc((size_t)ND*DH*2);
  bf16* outgb = (bf16*)alloc((size_t)NG*DH*2);
  bf16* outdb = (bf16*)alloc((size_t)ND*DH*2);

  // zero hist (960 ints) + bnsum (512 floats) in one memset (contiguous region)
  hipMemsetAsync(hist, 0, 960*4 + 512*4, stream);

  // --- CSR build: all 3 graphs ---
  {
    dim3 gh(96, 3);
    k_hist1<<<gh,256,0,stream>>>(gg_dst, gda_dst, gda_src, hist);
    k_exscan<<<1,1024,0,stream>>>(hist, gbase, gcur, TBP);
    dim3 gs(196, 3);
    k_scatter1<<<gs,256,0,stream>>>(gg_dst, gg_src, gda_dst, gda_src, gcur, pk);
    k_csr2<<<TB,256,0,stream>>>(pk, gbase, ptr_all, col);
  }

  // --- composed weights ---
  k_compose_AB<<<768,256,0,stream>>>(Wd1, Ws1, Wu1, Wd2, Ws2, Wu2, AB);
  k_compose_bias<<<3,256,0,stream>>>(bd1, bs1, bu1, Wu1, bd2, bs2, bu2, Wu2, cv);
  k_pack<<<640,256,0,stream>>>(AB, cv, Wg1, Wp1, Wg2, Wp2, cg1, cd1, cg2, cd2);

  // --- bf16 feature tables ---
  k_f2b<<<((NG+ND)*32+255)/256,256,0,stream>>>(x_gene, x_dis, (unsigned short*)xgb, (unsigned short*)xdb);

  // --- layer 1 ---
  k_agg<<<(NG+ND+NG)*16/256,256,0,stream>>>(xgb, xdb, ptr_all, col, aggGGb, aggGDAb, aggREVb);
  k_gemm<<<GBGENE+GBDIS,256,0,stream>>>(xgb, aggGGb, aggREVb, Wg1, cg1, (unsigned short*)outgb,
                                        xdb, aggGDAb, Wp1, cd1, (unsigned short*)outdb);
  k_bn_stats<<<SBG+SBD,256,0,stream>>>(outgb, outdb, bnsum);
  k_bn_apply<<<1024,256,0,stream>>>(outgb, outdb, bnsum, bng, bnb,
                                    (unsigned short*)Xg2b, (unsigned short*)Xd2b);

  // --- layer 2 ---
  k_agg<<<(NG+ND+NG)*16/256,256,0,stream>>>(Xg2b, Xd2b, ptr_all, col, aggGGb, aggGDAb, aggREVb);
  k_gemm<<<GBGENE+GBDIS,256,0,stream>>>(Xg2b, aggGGb, aggREVb, Wg2, cg2, (unsigned short*)outgb,
                                        Xd2b, aggGDAb, Wp2, cd2, (unsigned short*)outdb);

  // --- decoder ---
  k_decode<<<ELAB*16/256,256,0,stream>>>(outgb, outdb, lsrc, ldst, (float*)d_out, ELAB);
}

// Round 7
// 388.860 us; speedup vs baseline: 3.0332x; 1.0663x over previous
//
#include <hip/hip_runtime.h>
#include <hip/hip_bf16.h>
#include <cstddef>

#define NG   50000
#define ND   20000
#define DH   128
#define EGG  800000
#define EGDA 400000
#define ELAB 200000

// bucket layout: graph0 (gg by dst) 391, graph1 (gda by dst) 157, graph2 (gda by src) 391
#define B1G 391
#define B1D 157
#define TB  939            // total buckets
#define TBP 940            // padded (multiple of 4)
#define PB0 0
#define PB1 (NG+1)
#define PB2 (NG+1+ND+1)

typedef __hip_bfloat16  bf16;
typedef __attribute__((ext_vector_type(8))) short bf16x8;
typedef __attribute__((ext_vector_type(4))) float f32x4;

__device__ __forceinline__ float bf2f(short s){
  return __uint_as_float(((unsigned)(unsigned short)s) << 16);
}
__device__ __forceinline__ unsigned short f2b(float x){
  unsigned u = __float_as_uint(x);
  return (unsigned short)((u + 0x7FFF + ((u >> 16) & 1)) >> 16);
}

// ---------------- CSR build (all 3 graphs in one pass-set) ----------------
__global__ __launch_bounds__(256) void k_hist1(const int* __restrict__ k0, const int* __restrict__ k1,
                                               const int* __restrict__ k2, int* __restrict__ hist){
  __shared__ int lh[400];
  const int g = blockIdx.y;
  const int n  = (g == 0) ? EGG : EGDA;
  const int B1 = (g == 1) ? B1D : B1G;
  const int bb = (g == 0) ? 0 : (g == 1 ? B1G : B1G + B1D);
  const int* key = (g == 0) ? k0 : (g == 1 ? k1 : k2);
  for (int t = threadIdx.x; t < B1; t += 256) lh[t] = 0;
  __syncthreads();
  for (int i = blockIdx.x*blockDim.x + threadIdx.x; i < n; i += gridDim.x*blockDim.x)
    atomicAdd(&lh[key[i] >> 7], 1);
  __syncthreads();
  for (int t = threadIdx.x; t < B1; t += 256){
    int c = lh[t];
    if (c) atomicAdd(&hist[bb + t], c);
  }
}

__global__ __launch_bounds__(1024) void k_exscan(const int* __restrict__ cnt,
                                                 int* __restrict__ ptr, int* __restrict__ cur, int n){
  __shared__ int wsum[16];
  __shared__ int carry;
  const int tid = threadIdx.x, lane = tid & 63, wid = tid >> 6;
  if (tid == 0) carry = 0;
  __syncthreads();
  for (int base = 0; base < n; base += 4096){
    int i0 = base + tid*4;
    int4 v = {0,0,0,0};
    if (i0 < n) v = *(const int4*)(cnt + i0);
    int tsum = v.x + v.y + v.z + v.w;
    int x = tsum;
    #pragma unroll
    for (int off = 1; off < 64; off <<= 1){
      int t = __shfl_up(x, off);
      if (lane >= off) x += t;
    }
    if (lane == 63) wsum[wid] = x;
    __syncthreads();
    if (wid == 0 && lane < 16){
      int w = wsum[lane];
      #pragma unroll
      for (int off = 1; off < 16; off <<= 1){
        int t = __shfl_up(w, off);
        if (lane >= off) w += t;
      }
      wsum[lane] = w;
    }
    __syncthreads();
    int waveoff = wid ? wsum[wid-1] : 0;
    if (i0 < n){
      int ex = carry + waveoff + x - tsum;
      int4 o;
      o.x = ex; o.y = ex + v.x; o.z = o.y + v.y; o.w = o.z + v.z;
      *(int4*)(ptr + i0) = o;
      *(int4*)(cur + i0) = o;
    }
    int total = wsum[15];
    __syncthreads();
    if (tid == 0) carry += total;
    __syncthreads();
  }
  if (tid == 0) ptr[n] = carry;
}

__global__ __launch_bounds__(256) void k_scatter1(const int* __restrict__ k0, const int* __restrict__ v0,
                                                  const int* __restrict__ k1, const int* __restrict__ v1,
                                                  int* __restrict__ gcur, unsigned* __restrict__ pk){
  __shared__ int lh[400];
  __shared__ int base[400];
  const int g = blockIdx.y;
  const int n  = (g == 0) ? EGG : EGDA;
  const int B1 = (g == 1) ? B1D : B1G;
  const int bb = (g == 0) ? 0 : (g == 1 ? B1G : B1G + B1D);
  const int* key = (g == 0) ? k0 : (g == 1 ? k1 : v1);
  const int* val = (g == 0) ? v0 : (g == 1 ? v1 : k1);
  const int tid = threadIdx.x;
  const int chunk0 = blockIdx.x*4096;
  if (chunk0 >= n) return;
  for (int t = tid; t < B1; t += 256) lh[t] = 0;
  __syncthreads();
  int kd[16], vv[16];
  #pragma unroll
  for (int it = 0; it < 16; ++it){
    int i = chunk0 + it*256 + tid;
    int k = -1, v = 0;
    if (i < n){ k = key[i]; v = val[i]; atomicAdd(&lh[k >> 7], 1); }
    kd[it] = k; vv[it] = v;
  }
  __syncthreads();
  for (int t = tid; t < B1; t += 256){
    int c = lh[t];
    base[t] = c ? atomicAdd(&gcur[bb + t], c) : 0;
    lh[t] = 0;
  }
  __syncthreads();
  #pragma unroll
  for (int it = 0; it < 16; ++it){
    int k = kd[it];
    if (k >= 0){
      int b = k >> 7;
      int p = base[b] + atomicAdd(&lh[b], 1);
      pk[p] = ((unsigned)(k & 127) << 17) | (unsigned)vv[it];
    }
  }
}

__global__ __launch_bounds__(256) void k_csr2(const unsigned* __restrict__ pk,
                                              const int* __restrict__ gbase,
                                              int* __restrict__ ptr_all, int* __restrict__ col){
  __shared__ int lh[128];
  __shared__ int cur[128];
  __shared__ int sh0;
  const int b = blockIdx.x, tid = threadIdx.x;
  int g, lb, pbase, Ngr, bend;
  if (b < B1G)            { g = 0; lb = b;            pbase = PB0; Ngr = NG; bend = B1G; }
  else if (b < B1G + B1D) { g = 1; lb = b - B1G;      pbase = PB1; Ngr = ND; bend = B1G + B1D; }
  else                    { g = 2; lb = b - B1G - B1D; pbase = PB2; Ngr = NG; bend = TB; }
  const int s = gbase[b], e = gbase[b+1];
  if (tid < 128) lh[tid] = 0;
  __syncthreads();
  for (int i = s + tid; i < e; i += 256)
    atomicAdd(&lh[(pk[i] >> 17) & 127], 1);
  __syncthreads();
  int lane = tid & 63;
  int v = 0, x = 0;
  if (tid < 128){
    v = lh[tid]; x = v;
    #pragma unroll
    for (int o = 1; o < 64; o <<= 1){
      int t = __shfl_up(x, o);
      if (lane >= o) x += t;
    }
    if (tid == 63) sh0 = x;
  }
  __syncthreads();
  if (tid < 128){
    int excl = x - v + (tid >= 64 ? sh0 : 0);
    cur[tid] = s + excl;
    int loc = (lb << 7) + tid;
    if (loc < Ngr) ptr_all[pbase + loc] = s + excl;
  }
  __syncthreads();
  for (int i = s + tid; i < e; i += 256){
    unsigned p = pk[i];
    int dl = (p >> 17) & 127;
    int pos = atomicAdd(&cur[dl], 1);
    col[pos] = (int)(p & 0x1FFFFu);
  }
  if (lb == 0 && tid == 0) ptr_all[pbase + Ngr] = gbase[bend];
}

// ---------------- weight composition (both layers fused) ----------------
__global__ __launch_bounds__(256) void k_compose_AB(
    const float* __restrict__ Wd1, const float* __restrict__ Ws1, const float* __restrict__ Wu1,
    const float* __restrict__ Wd2, const float* __restrict__ Ws2, const float* __restrict__ Wu2,
    float* __restrict__ AB){
  int idx = blockIdx.x*256 + threadIdx.x;       // 2*6*16384
  int layer = idx / 98304;
  int r0 = idx - layer*98304;
  int mat = r0 >> 14;
  int r   = (r0 >> 7) & 127;
  int c   = r0 & 127;
  int i   = mat >> 1;
  int isB = mat & 1;
  const float* Wd = layer ? Wd2 : Wd1;
  const float* Ws = layer ? Ws2 : Ws1;
  const float* Wu = layer ? Wu2 : Wu1;
  const float* P = (isB ? Ws : Wd) + i*16384 + r*128;
  const float* Q = Wu + i*32768 + (isB ? 16384 : 0) + c;
  float s = 0.f;
  for (int h = 0; h < 128; ++h) s += P[h] * Q[h*128];
  AB[idx] = s;
}

__global__ __launch_bounds__(256) void k_compose_bias(
    const float* __restrict__ bd1, const float* __restrict__ bs1, const float* __restrict__ bu1, const float* __restrict__ Wu1,
    const float* __restrict__ bd2, const float* __restrict__ bs2, const float* __restrict__ bu2, const float* __restrict__ Wu2,
    float* __restrict__ cv){
  int idx = blockIdx.x*256 + threadIdx.x;       // 2*384
  if (idx >= 768) return;
  int layer = idx / 384;
  int r = idx - layer*384;
  int i = r >> 7, h = r & 127;
  const float* bd = layer ? bd2 : bd1;
  const float* bs = layer ? bs2 : bs1;
  const float* bu = layer ? bu2 : bu1;
  const float* Wu = layer ? Wu2 : Wu1;
  float s = bu[i*128 + h];
  const float* Ut = Wu + i*32768 + h;
  const float* Ub = Ut + 16384;
  for (int k = 0; k < 128; ++k)
    s += bd[i*128 + k] * Ut[k*128] + bs[i*128 + k] * Ub[k*128];
  cv[idx] = s;
}

// pack B-fragment order (hi-only), both layers + gene/dis in one kernel
__global__ __launch_bounds__(256) void k_pack(const float* __restrict__ AB, const float* __restrict__ cv,
                                              bf16* __restrict__ Wg1, bf16* __restrict__ Wd1p,
                                              bf16* __restrict__ Wg2, bf16* __restrict__ Wd2p,
                                              float* __restrict__ cg1, float* __restrict__ cd1,
                                              float* __restrict__ cg2, float* __restrict__ cd2){
  int idx = blockIdx.x*256 + threadIdx.x;       // 2*(49152+32768) = 163840
  int layer = idx / 81920;
  int rem = idx - layer*81920;
  const float* ABl = AB + layer*98304;
  const float* cvl = cv + layer*384;
  if (rem < 49152){
    int n0  = rem / 6144;
    int r2  = rem - n0*6144;
    int ks  = r2 >> 9;
    int lane = (r2 >> 3) & 63;
    int j   = r2 & 7;
    int k   = ks*32 + (lane >> 4)*8 + j;
    int c   = n0*16 + (lane & 15);
    float v;
    if      (k < 128) v = 0.5f*(ABl[0*16384 + k*128 + c] + ABl[4*16384 + k*128 + c]);
    else if (k < 256) v = 0.5f* ABl[1*16384 + (k-128)*128 + c];
    else              v = 0.5f* ABl[5*16384 + (k-256)*128 + c];
    bf16* W = layer ? Wg2 : Wg1;
    ((unsigned short*)W)[rem] = f2b(v);
    if (rem < 128){
      float* cg = layer ? cg2 : cg1;
      cg[rem] = 0.5f*(cvl[rem] + cvl[256 + rem]);
    }
  } else {
    int d = rem - 49152;
    int n0  = d >> 12;
    int ks  = (d >> 9) & 7;
    int lane = (d >> 3) & 63;
    int j   = d & 7;
    int k   = ks*32 + (lane >> 4)*8 + j;
    int c   = n0*16 + (lane & 15);
    float v = (k < 128) ? ABl[2*16384 + k*128 + c] : ABl[3*16384 + (k-128)*128 + c];
    bf16* W = layer ? Wd2p : Wd1p;
    ((unsigned short*)W)[d] = f2b(v);
    if (d < 128){
      float* cd = layer ? cd2 : cd1;
      cd[d] = cvl[128 + d];
    }
  }
}

// ---------------- fp32 -> bf16 tables (both) ----------------
__global__ __launch_bounds__(256) void k_f2b(const float* __restrict__ Xg, const float* __restrict__ Xd,
                                             unsigned short* __restrict__ Yg, unsigned short* __restrict__ Yd){
  int idx = blockIdx.x*256 + threadIdx.x;       // (NG+ND)*32
  const int GQ = NG*32;
  if (idx >= GQ + ND*32) return;
  const float* X; unsigned short* Y; int i;
  if (idx < GQ){ X = Xg; Y = Yg; i = idx; }
  else         { X = Xd; Y = Yd; i = idx - GQ; }
  float4 v = ((const float4*)X)[i];
  ushort4 o;
  o.x = f2b(v.x); o.y = f2b(v.y); o.z = f2b(v.z); o.w = f2b(v.w);
  ((ushort4*)Y)[i] = o;
}

// ---------------- mean aggregation: 3 graphs, one kernel, 4x-unrolled MLP ----------------
__global__ __launch_bounds__(256) void k_agg(const bf16* __restrict__ Xg, const bf16* __restrict__ Xd,
    const int* __restrict__ ptr_all, const int* __restrict__ col,
    bf16* __restrict__ OutGG, bf16* __restrict__ OutGDA, bf16* __restrict__ OutREV){
  int q = (blockIdx.x*256 + threadIdx.x) >> 4;
  int lane = threadIdx.x & 15;
  const bf16* X; bf16* Out; const int* ptr; int dst;
  if (q < NG)          { X = Xg; Out = OutGG;  ptr = ptr_all + PB0; dst = q; }
  else if (q < NG+ND)  { X = Xg; Out = OutGDA; ptr = ptr_all + PB1; dst = q - NG; }
  else                 { X = Xd; Out = OutREV; ptr = ptr_all + PB2; dst = q - NG - ND; }
  int s = ptr[dst], e = ptr[dst+1];
  float a[8];
  #pragma unroll
  for (int j = 0; j < 8; ++j) a[j] = 0.f;
  const size_t loff = (size_t)lane*8;
  int i = s;
  for (; i + 4 <= e; i += 4){
    int c0 = col[i], c1 = col[i+1], c2 = col[i+2], c3 = col[i+3];
    bf16x8 v0 = *(const bf16x8*)(X + (size_t)c0*DH + loff);
    bf16x8 v1 = *(const bf16x8*)(X + (size_t)c1*DH + loff);
    bf16x8 v2 = *(const bf16x8*)(X + (size_t)c2*DH + loff);
    bf16x8 v3 = *(const bf16x8*)(X + (size_t)c3*DH + loff);
    #pragma unroll
    for (int j = 0; j < 8; ++j)
      a[j] += (bf2f(v0[j]) + bf2f(v1[j])) + (bf2f(v2[j]) + bf2f(v3[j]));
  }
  for (; i < e; ++i){
    bf16x8 v = *(const bf16x8*)(X + (size_t)col[i]*DH + loff);
    #pragma unroll
    for (int j = 0; j < 8; ++j) a[j] += bf2f(v[j]);
  }
  float inv = 1.f / fmaxf((float)(e - s), 1.f);
  bf16x8 o;
  #pragma unroll
  for (int j = 0; j < 8; ++j) o[j] = (short)f2b(a[j]*inv);
  *(bf16x8*)(Out + (size_t)dst*DH + loff) = o;
}

// ---------------- concat-K MFMA GEMM: no LDS, B from global (L2), hi-only ----------------
template<int KS>
__device__ __forceinline__ void gemm_body(
    const bf16* __restrict__ X0, const bf16* __restrict__ X1, const bf16* __restrict__ X2,
    const bf16* __restrict__ Wp, const float* __restrict__ cvec,
    unsigned short* __restrict__ Out, int M, int blk){
  const int tid = threadIdx.x;
  const int wave = tid >> 6, lane = tid & 63;
  const int lrow = lane & 15, quad = lane >> 4;
  const int row0 = blk*64;
  const bf16* Xs[3] = {X0, X1, X2};
  f32x4 acc[2][4];
  #pragma unroll
  for (int p = 0; p < 2; ++p)
    #pragma unroll
    for (int t = 0; t < 4; ++t) acc[p][t] = 0.0f;
  const bf16x8* wp = (const bf16x8*)Wp;
  const int f00 = (2*wave*KS)*64 + lane;
  #pragma unroll
  for (int ks = 0; ks < KS; ++ks){
    const bf16* Xm = Xs[ks >> 2];
    const int kk = (ks & 3)*32 + quad*8;
    bf16x8 a[4];
    #pragma unroll
    for (int t = 0; t < 4; ++t){
      int ar = row0 + t*16 + lrow; if (ar > M-1) ar = M-1;
      a[t] = *(const bf16x8*)(Xm + (size_t)ar*DH + kk);
    }
    bf16x8 b0 = wp[f00 + ks*64];
    bf16x8 b1 = wp[f00 + (KS + ks)*64];
    #pragma unroll
    for (int t = 0; t < 4; ++t){
      acc[0][t] = __builtin_amdgcn_mfma_f32_16x16x32_bf16(a[t], b0, acc[0][t], 0, 0, 0);
      acc[1][t] = __builtin_amdgcn_mfma_f32_16x16x32_bf16(a[t], b1, acc[1][t], 0, 0, 0);
    }
  }
  #pragma unroll
  for (int p = 0; p < 2; ++p){
    int c = (2*wave + p)*16 + lrow;
    float cb = cvec[c];
    #pragma unroll
    for (int t = 0; t < 4; ++t){
      #pragma unroll
      for (int r = 0; r < 4; ++r){
        int row = row0 + t*16 + quad*4 + r;
        if (row < M) Out[(size_t)row*DH + c] = f2b(acc[p][t][r] + cb);
      }
    }
  }
}

#define GBGENE ((NG+63)/64)
#define GBDIS  ((ND+63)/64)

__global__ __launch_bounds__(256) void k_gemm(
    const bf16* __restrict__ Xg, const bf16* __restrict__ Ag, const bf16* __restrict__ Rg,
    const bf16* __restrict__ Wg, const float* __restrict__ cg, unsigned short* __restrict__ Og,
    const bf16* __restrict__ Xd, const bf16* __restrict__ Ad,
    const bf16* __restrict__ Wd, const float* __restrict__ cd, unsigned short* __restrict__ Od){
  if ((int)blockIdx.x < GBGENE)
    gemm_body<12>(Xg, Ag, Rg, Wg, cg, Og, NG, blockIdx.x);
  else
    gemm_body<8>(Xd, Ad, Ad, Wd, cd, Od, ND, blockIdx.x - GBGENE);
}

// ---------------- BatchNorm stats (both matrices, one kernel) ----------------
#define SBG 192
#define SBD 64
__global__ __launch_bounds__(256) void k_bn_stats(const bf16* __restrict__ Xgb, const bf16* __restrict__ Xdb,
                                                  float* __restrict__ sums){
  __shared__ float acc[256];
  int tid = threadIdx.x;
  acc[tid] = 0.f;
  __syncthreads();
  int g = (int)blockIdx.x >= SBG;
  int bidx = blockIdx.x - (g ? SBG : 0);
  int NB = g ? SBD : SBG;
  int N  = g ? ND : NG;
  const bf16* Xb = g ? Xdb : Xgb;
  float* sm = sums + g*256;
  int c8 = (tid & 15)*8;
  int rl = tid >> 4;
  float s[8], q[8];
  #pragma unroll
  for (int j = 0; j < 8; ++j){ s[j] = 0.f; q[j] = 0.f; }
  for (int r = bidx*16 + rl; r < N; r += NB*16){
    bf16x8 v = *(const bf16x8*)(Xb + (size_t)r*DH + c8);
    #pragma unroll
    for (int j = 0; j < 8; ++j){
      float f = bf2f(v[j]);
      s[j] += f; q[j] += f*f;
    }
  }
  #pragma unroll
  for (int j = 0; j < 8; ++j){
    atomicAdd(&acc[c8+j], s[j]);
    atomicAdd(&acc[128+c8+j], q[j]);
  }
  __syncthreads();
  atomicAdd(&sm[tid], acc[tid]);
}

// BN + LeakyReLU, both matrices
__global__ __launch_bounds__(256) void k_bn_apply(const bf16* __restrict__ Xgb, const bf16* __restrict__ Xdb,
    const float* __restrict__ sums, const float* __restrict__ gamma, const float* __restrict__ beta,
    unsigned short* __restrict__ Yg, unsigned short* __restrict__ Yd){
  __shared__ float sc[256], sb[256];
  int tid = threadIdx.x;
  {
    int g = tid >> 7, c = tid & 127;
    float invN = g ? (1.f/ND) : (1.f/NG);
    const float* sm = sums + g*256;
    float m = sm[c]*invN;
    float v = sm[128 + c]*invN - m*m;
    float s = rsqrtf(v + 1e-5f) * gamma[g*128 + c];
    sc[tid] = s;
    sb[tid] = beta[g*128 + c] - m*s;
  }
  __syncthreads();
  const int GT = NG*16;
  const int TOT = GT + ND*16;
  for (int idx = blockIdx.x*256 + tid; idx < TOT; idx += gridDim.x*256){
    const bf16x8* src; bf16x8* dst; int i, cb;
    if (idx < GT){ src = (const bf16x8*)Xgb; dst = (bf16x8*)Yg; i = idx; cb = 0; }
    else         { src = (const bf16x8*)Xdb; dst = (bf16x8*)Yd; i = idx - GT; cb = 128; }
    bf16x8 v = src[i];
    int c = cb + (i & 15)*8;
    bf16x8 o;
    #pragma unroll
    for (int j = 0; j < 8; ++j){
      float y = bf2f(v[j])*sc[c+j] + sb[c+j];
      y = y >= 0.f ? y : 0.01f*y;
      o[j] = (short)f2b(y);
    }
    dst[i] = o;
  }
}

// ---------------- decoder: 2 edges per quarter-wave (4 gathers in flight) ----------------
__global__ __launch_bounds__(256) void k_decode(const bf16* __restrict__ G, const bf16* __restrict__ Dd,
    const int* __restrict__ ls, const int* __restrict__ ld, float* __restrict__ out, int E){
  int p = (blockIdx.x*256 + threadIdx.x) >> 4;
  int lane = threadIdx.x & 15;
  int e0 = p*2, e1 = p*2 + 1;
  if (e0 >= E) return;
  int a0 = ls[e0], b0 = ld[e0];
  int a1 = ls[e1], b1 = ld[e1];
  const size_t loff = (size_t)lane*8;
  bf16x8 g0 = *(const bf16x8*)(G  + (size_t)a0*DH + loff);
  bf16x8 d0 = *(const bf16x8*)(Dd + (size_t)b0*DH + loff);
  bf16x8 g1 = *(const bf16x8*)(G  + (size_t)a1*DH + loff);
  bf16x8 d1 = *(const bf16x8*)(Dd + (size_t)b1*DH + loff);
  float s0 = 0.f, s1 = 0.f;
  #pragma unroll
  for (int j = 0; j < 8; ++j){
    s0 += bf2f(g0[j])*bf2f(d0[j]);
    s1 += bf2f(g1[j])*bf2f(d1[j]);
  }
  #pragma unroll
  for (int off = 8; off; off >>= 1){
    s0 += __shfl_down(s0, off, 16);
    s1 += __shfl_down(s1, off, 16);
  }
  if (lane == 0){ out[e0] = s0; out[e1] = s1; }
}

// ---------------- launch ----------------
extern "C" void kernel_launch(void* const* d_in, const int* in_sizes, int n_in,
                              void* d_out, int out_size, void* d_ws, size_t ws_size,
                              hipStream_t stream){
  const float* x_gene = (const float*)d_in[0];
  const float* x_dis  = (const float*)d_in[1];
  const float* Wd1 = (const float*)d_in[2];
  const float* Ws1 = (const float*)d_in[3];
  const float* Wu1 = (const float*)d_in[4];
  const float* bd1 = (const float*)d_in[5];
  const float* bs1 = (const float*)d_in[6];
  const float* bu1 = (const float*)d_in[7];
  const float* Wd2 = (const float*)d_in[8];
  const float* Ws2 = (const float*)d_in[9];
  const float* Wu2 = (const float*)d_in[10];
  const float* bd2 = (const float*)d_in[11];
  const float* bs2 = (const float*)d_in[12];
  const float* bu2 = (const float*)d_in[13];
  const float* bng = (const float*)d_in[14];
  const float* bnb = (const float*)d_in[15];
  const int* gg_src  = (const int*)d_in[16];
  const int* gg_dst  = (const int*)d_in[17];
  const int* gda_src = (const int*)d_in[18];
  const int* gda_dst = (const int*)d_in[19];
  const int* lsrc = (const int*)d_in[20];
  const int* ldst = (const int*)d_in[21];

  char* ws = (char*)d_ws;
  size_t off = 0;
  auto alloc = [&](size_t bytes)->void*{
    void* p = ws + off; off += (bytes + 255) & ~(size_t)255; return p;
  };
  int* hist    = (int*)alloc(960*4);
  float* bnsum = (float*)alloc(2*256*4);
  int* gbase   = (int*)alloc(960*4);
  int* gcur    = (int*)alloc(960*4);
  int* ptr_all = (int*)alloc((size_t)(NG+1+ND+1+NG+1)*4);
  int* col     = (int*)alloc((size_t)(EGG+2*EGDA)*4);
  unsigned* pk = (unsigned*)alloc((size_t)(EGG+2*EGDA)*4);
  float* AB  = (float*)alloc(2*98304*4);
  float* cv  = (float*)alloc(2*384*4);
  float* cg1 = (float*)alloc(128*4);
  float* cd1 = (float*)alloc(128*4);
  float* cg2 = (float*)alloc(128*4);
  float* cd2 = (float*)alloc(128*4);
  bf16* Wg1  = (bf16*)alloc(49152*2);
  bf16* Wp1  = (bf16*)alloc(32768*2);
  bf16* Wg2  = (bf16*)alloc(49152*2);
  bf16* Wp2  = (bf16*)alloc(32768*2);
  bf16* xgb  = (bf16*)alloc((size_t)NG*DH*2);
  bf16* xdb  = (bf16*)alloc((size_t)ND*DH*2);
  bf16* aggGGb  = (bf16*)alloc((size_t)NG*DH*2);
  bf16* aggREVb = (bf16*)alloc((size_t)NG*DH*2);
  bf16* aggGDAb = (bf16*)alloc((size_t)ND*DH*2);
  bf16* Xg2b = (bf16*)alloc((size_t)NG*DH*2);
  bf16* Xd2b = (bf16*)alloc((size_t)ND*DH*2);
  bf16* outgb = (bf16*)alloc((size_t)NG*DH*2);
  bf16* outdb = (bf16*)alloc((size_t)ND*DH*2);

  hipMemsetAsync(hist, 0, 960*4 + 512*4, stream);

  // --- CSR build: all 3 graphs ---
  {
    dim3 gh(96, 3);
    k_hist1<<<gh,256,0,stream>>>(gg_dst, gda_dst, gda_src, hist);
    k_exscan<<<1,1024,0,stream>>>(hist, gbase, gcur, TBP);
    dim3 gs(196, 3);
    k_scatter1<<<gs,256,0,stream>>>(gg_dst, gg_src, gda_dst, gda_src, gcur, pk);
    k_csr2<<<TB,256,0,stream>>>(pk, gbase, ptr_all, col);
  }

  // --- composed weights ---
  k_compose_AB<<<768,256,0,stream>>>(Wd1, Ws1, Wu1, Wd2, Ws2, Wu2, AB);
  k_compose_bias<<<3,256,0,stream>>>(bd1, bs1, bu1, Wu1, bd2, bs2, bu2, Wu2, cv);
  k_pack<<<640,256,0,stream>>>(AB, cv, Wg1, Wp1, Wg2, Wp2, cg1, cd1, cg2, cd2);

  // --- bf16 feature tables ---
  k_f2b<<<((NG+ND)*32+255)/256,256,0,stream>>>(x_gene, x_dis, (unsigned short*)xgb, (unsigned short*)xdb);

  // --- layer 1 ---
  k_agg<<<(NG+ND+NG)*16/256,256,0,stream>>>(xgb, xdb, ptr_all, col, aggGGb, aggGDAb, aggREVb);
  k_gemm<<<GBGENE+GBDIS,256,0,stream>>>(xgb, aggGGb, aggREVb, Wg1, cg1, (unsigned short*)outgb,
                                        xdb, aggGDAb, Wp1, cd1, (unsigned short*)outdb);
  k_bn_stats<<<SBG+SBD,256,0,stream>>>(outgb, outdb, bnsum);
  k_bn_apply<<<1024,256,0,stream>>>(outgb, outdb, bnsum, bng, bnb,
                                    (unsigned short*)Xg2b, (unsigned short*)Xd2b);

  // --- layer 2 ---
  k_agg<<<(NG+ND+NG)*16/256,256,0,stream>>>(Xg2b, Xd2b, ptr_all, col, aggGGb, aggGDAb, aggREVb);
  k_gemm<<<GBGENE+GBDIS,256,0,stream>>>(Xg2b, aggGGb, aggREVb, Wg2, cg2, (unsigned short*)outgb,
                                        Xd2b, aggGDAb, Wp2, cd2, (unsigned short*)outdb);

  // --- decoder ---
  k_decode<<<ELAB*16/2/256,256,0,stream>>>(outgb, outdb, lsrc, ldst, (float*)d_out, ELAB);
}